// Round 12
// baseline (477.186 us; speedup 1.0000x reference)
//
#include <hip/hip_runtime.h>

#define BB 4
#define LL 48
#define TT 16
#define NWW 20
#define DD 256
#define DLL 64

typedef __attribute__((ext_vector_type(8))) short s8v;
typedef __attribute__((ext_vector_type(4))) float f4v;
typedef unsigned short ushort_t;

#define FENCE() asm volatile("" ::: "memory")

// ---- ws layout (bytes) ----
#define OFF_CU     0ull           // bf16 cu state (FRAGMENT order): 75,497,472
#define OFF_CM     75497472ull
#define OFF_BU0    84934656ull
#define OFF_BU1    85131264ull
#define OFF_FBQ    85327872ull
#define OFF_FWH    85524480ull
#define OFF_FSH    85544960ull
#define OFF_KB     85545984ull
#define OFF_BWQT   85627904ull
#define OFF_WBT    85890048ull
#define OFF_WCT    85899264ull
#define OFF_DCCF   85908480ull
#define OFF_CWQF   85941248ull
#define OFF_UCCF   85949440ull
#define OFF_KCF    85982208ull
#define OFF_FWHTF  85998592ull

static __device__ __forceinline__ ushort_t f2bf(float f){
  unsigned u = __float_as_uint(f);
  return (ushort_t)((u + 0x7FFFu + ((u>>16)&1u)) >> 16);
}
static __device__ __forceinline__ float bf2f(ushort_t h){
  return __uint_as_float(((unsigned)h)<<16);
}
static __device__ __forceinline__ void st64(void* p, float a, float b, float c, float d){
  uint2 v; v.x = (unsigned)f2bf(a) | ((unsigned)f2bf(b)<<16);
  v.y = (unsigned)f2bf(c) | ((unsigned)f2bf(d)<<16);
  *(uint2*)p = v;
}

#define ADR64(row, cb) (((row)<<7) + ((cb) ^ (((row)&7)<<4)))
#define ADR32(row, cb) (((row)<<6) + ((cb) ^ (((row)&3)<<4)))

#define MFMA(a,b,c) __builtin_amdgcn_mfma_f32_16x16x32_bf16((a),(b),(c),0,0,0)

// =====================================================================
// CONTENT UNIT: 2 waves/block, TWO tiles per wave (A,B) interleaved
// through every phase: each A-fragment load feeds 2 MFMAs; tile B's
// compute hides tile A's LDS/mem latency. Private 8 KB LDS per tile,
// no hardware barriers. cu in FRAGMENT ORDER (see R11).
// =====================================================================
template<int FIRST>
__global__ __launch_bounds__(128)
void content_kernel(const void* cusrc_, ushort_t* cudst, float* __restrict__ cm,
                    const float* __restrict__ fm_src, const float* __restrict__ fsg,
                    const float* __restrict__ fsh, const float* __restrict__ dccb,
                    const float* __restrict__ cbq, const float* __restrict__ uccb,
                    const ushort_t* __restrict__ dccf, const ushort_t* __restrict__ cwqf,
                    const ushort_t* __restrict__ uccf, const ushort_t* __restrict__ kcf,
                    const ushort_t* __restrict__ fwhtf)
{
  __shared__ __align__(16) char sm_all[4][8192];
  const int wid = threadIdx.x >> 6;
  const int lane = threadIdx.x & 63;
  char* smA = sm_all[wid*2];
  char* smB = sm_all[wid*2+1];
  const int t = lane & 15, g = lane >> 4;
  const int tileA = blockIdx.x*4 + wid*2;
  const int tileB = tileA + 1;
  const int b = tileA / (LL*LL);   // tiles/b = 2304, 4 | 2304 -> same b for A,B

  { f4v z = {0.f,0.f,0.f,0.f};
    *(f4v*)(smA + 4096 + ADR32(lane, 32)) = z;
    *(f4v*)(smA + 4096 + ADR32(lane, 48)) = z;
    *(f4v*)(smB + 4096 + ADR32(lane, 32)) = z;
    *(f4v*)(smB + 4096 + ADR32(lane, 48)) = z; }

  // ---- X B-fragments for both tiles ----
  s8v xbA[8], xbB[8];
  if (FIRST){
    const float* xpA = (const float*)cusrc_ + (size_t)tileA*4096 + t*DD + g*8;
    const float* xpB = (const float*)cusrc_ + (size_t)tileB*4096 + t*DD + g*8;
    #pragma unroll
    for (int kk=0;kk<8;kk++){
      f4v lo = *(const f4v*)(xpA + kk*32);
      f4v hi = *(const f4v*)(xpA + kk*32 + 4);
      s8v v;
      v[0]=(short)f2bf(lo[0]); v[1]=(short)f2bf(lo[1]);
      v[2]=(short)f2bf(lo[2]); v[3]=(short)f2bf(lo[3]);
      v[4]=(short)f2bf(hi[0]); v[5]=(short)f2bf(hi[1]);
      v[6]=(short)f2bf(hi[2]); v[7]=(short)f2bf(hi[3]);
      xbA[kk]=v;
      lo = *(const f4v*)(xpB + kk*32);
      hi = *(const f4v*)(xpB + kk*32 + 4);
      v[0]=(short)f2bf(lo[0]); v[1]=(short)f2bf(lo[1]);
      v[2]=(short)f2bf(lo[2]); v[3]=(short)f2bf(lo[3]);
      v[4]=(short)f2bf(hi[0]); v[5]=(short)f2bf(hi[1]);
      v[6]=(short)f2bf(hi[2]); v[7]=(short)f2bf(hi[3]);
      xbB[kk]=v;
    }
  } else {
    const ushort_t* xpA = (const ushort_t*)cusrc_ + (size_t)tileA*4096 + lane*8;
    const ushort_t* xpB = (const ushort_t*)cusrc_ + (size_t)tileB*4096 + lane*8;
    #pragma unroll
    for (int kk=0;kk<8;kk++){
      xbA[kk] = *(const s8v*)(xpA + kk*512);
      xbB[kk] = *(const s8v*)(xpB + kk*512);
    }
  }

  // ---- H phase: one dccf load -> 2 MFMAs ----
  f4v accHA[4], accHB[4];
  { f4v z = {0.f,0.f,0.f,0.f};
    accHA[0]=z;accHA[1]=z;accHA[2]=z;accHA[3]=z;
    accHB[0]=z;accHB[1]=z;accHB[2]=z;accHB[3]=z; }
  #pragma unroll
  for (int kk=0;kk<8;kk++){
    #pragma unroll
    for (int m0=0;m0<4;m0++){
      s8v a = *(const s8v*)(dccf + (((m0<<3)+kk)<<9) + (lane<<3));
      accHA[m0] = MFMA(a, xbA[kk], accHA[m0]);
      accHB[m0] = MFMA(a, xbB[kk], accHB[m0]);
    }
  }
  s8v cwa[8];
  #pragma unroll
  for (int i=0;i<8;i++) cwa[i] = *(const s8v*)(cwqf + (i<<9) + (lane<<3));
  #pragma unroll
  for (int m0=0;m0<4;m0++){
    f4v bi = *(const f4v*)(dccb + m0*16 + g*4);
    f4v a1 = accHA[m0];
    a1[0]+=bi[0]; a1[1]+=bi[1]; a1[2]+=bi[2]; a1[3]+=bi[3];
    accHA[m0]=a1;
    st64(smA + ADR64(t, m0*32 + g*8), a1[0],a1[1],a1[2],a1[3]);
    f4v a2 = accHB[m0];
    a2[0]+=bi[0]; a2[1]+=bi[1]; a2[2]+=bi[2]; a2[3]+=bi[3];
    accHB[m0]=a2;
    st64(smB + ADR64(t, m0*32 + g*8), a2[0],a2[1],a2[2],a2[3]);
    #pragma unroll
    for (int r=0;r<4;r++){
      *(ushort_t*)(smA + 4096 + ADR32(m0*16 + g*4 + r, t*2)) = f2bf(a1[r]);
      *(ushort_t*)(smB + 4096 + ADR32(m0*16 + g*4 + r, t*2)) = f2bf(a2[r]);
    }
  }
  FENCE();  // A

  // ---- Q phase ----
  s8v hbA0 = *(const s8v*)(smA + ADR64(t, g*16));
  s8v hbA1 = *(const s8v*)(smA + ADR64(t, 64 + g*16));
  s8v hbB0 = *(const s8v*)(smB + ADR64(t, g*16));
  s8v hbB1 = *(const s8v*)(smB + ADR64(t, 64 + g*16));
  #pragma unroll
  for (int m0=0;m0<4;m0++){
    f4v bi = *(const f4v*)(cbq + m0*16 + g*4);
    f4v aa = {0.f,0.f,0.f,0.f};
    aa = MFMA(cwa[m0*2  ], hbA0, aa);
    aa = MFMA(cwa[m0*2+1], hbA1, aa);
    st64(smA + 2048 + ADR64(t, m0*32 + g*8),
         aa[0]+bi[0], aa[1]+bi[1], aa[2]+bi[2], aa[3]+bi[3]);
    f4v ab = {0.f,0.f,0.f,0.f};
    ab = MFMA(cwa[m0*2  ], hbB0, ab);
    ab = MFMA(cwa[m0*2+1], hbB1, ab);
    st64(smB + 2048 + ADR64(t, m0*32 + g*8),
         ab[0]+bi[0], ab[1]+bi[1], ab[2]+bi[2], ab[3]+bi[3]);
  }
  s8v kca[4];
  #pragma unroll
  for (int i=0;i<4;i++) kca[i] = *(const s8v*)(kcf + (b<<11) + (i<<9) + (lane<<3));
  FENCE();  // B

  // ---- s phase + softmax (both tiles) ----
  s8v qbA0 = *(const s8v*)(smA + 2048 + ADR64(t, g*16));
  s8v qbA1 = *(const s8v*)(smA + 2048 + ADR64(t, 64 + g*16));
  s8v qbB0 = *(const s8v*)(smB + 2048 + ADR64(t, g*16));
  s8v qbB1 = *(const s8v*)(smB + 2048 + ADR64(t, 64 + g*16));
  f4v sAA[2], sAB[2];
  #pragma unroll
  for (int m0=0;m0<2;m0++){
    f4v aa = {0.f,0.f,0.f,0.f};
    aa = MFMA(kca[m0*2  ], qbA0, aa);
    aa = MFMA(kca[m0*2+1], qbA1, aa);
    sAA[m0]=aa;
    f4v ab = {0.f,0.f,0.f,0.f};
    ab = MFMA(kca[m0*2  ], qbB0, ab);
    ab = MFMA(kca[m0*2+1], qbB1, ab);
    sAB[m0]=ab;
  }
  {
    float mxA = -3.0e38f, mxB = -3.0e38f;
    #pragma unroll
    for (int m0=0;m0<2;m0++){
      #pragma unroll
      for (int r=0;r<4;r++){
        int n = m0*16 + g*4 + r;
        if (n < NWW){ mxA = fmaxf(mxA, sAA[m0][r]); mxB = fmaxf(mxB, sAB[m0][r]); }
      }
    }
    mxA = fmaxf(mxA, __shfl_xor(mxA, 16)); mxA = fmaxf(mxA, __shfl_xor(mxA, 32));
    mxB = fmaxf(mxB, __shfl_xor(mxB, 16)); mxB = fmaxf(mxB, __shfl_xor(mxB, 32));
    float exA[8], exB[8]; float suA = 0.f, suB = 0.f;
    #pragma unroll
    for (int m0=0;m0<2;m0++){
      #pragma unroll
      for (int r=0;r<4;r++){
        int n = m0*16 + g*4 + r;
        float eA = (n < NWW) ? __expf(sAA[m0][r]-mxA) : 0.f;
        float eB = (n < NWW) ? __expf(sAB[m0][r]-mxB) : 0.f;
        exA[m0*4+r]=eA; suA+=eA;
        exB[m0*4+r]=eB; suB+=eB;
      }
    }
    suA += __shfl_xor(suA,16); suA += __shfl_xor(suA,32);
    suB += __shfl_xor(suB,16); suB += __shfl_xor(suB,32);
    float ivA = 1.f/suA, ivB = 1.f/suB;
    #pragma unroll
    for (int m0=0;m0<2;m0++){
      st64(smA + ADR32(t, m0*32 + g*8),
           exA[m0*4]*ivA, exA[m0*4+1]*ivA, exA[m0*4+2]*ivA, exA[m0*4+3]*ivA);
      st64(smB + ADR32(t, m0*32 + g*8),
           exB[m0*4]*ivB, exB[m0*4+1]*ivB, exB[m0*4+2]*ivB, exB[m0*4+3]*ivB);
    }
  }
  s8v fwa[4];
  #pragma unroll
  for (int i=0;i<4;i++) fwa[i] = *(const s8v*)(fwhtf + (b<<11) + (i<<9) + (lane<<3));
  FENCE();  // C

  // ---- fcaq / f_cq (hi/lo split) ----
  s8v awbA = *(const s8v*)(smA + ADR32(t, g*16));
  s8v awbB = *(const s8v*)(smB + ADR32(t, g*16));
  FENCE();  // C2
  #pragma unroll
  for (int m0=0;m0<4;m0++){
    f4v z = {0.f,0.f,0.f,0.f};
    f4v fv = *(const f4v*)(fsh + b*DLL + m0*16 + g*4);
    f4v aa = MFMA(fwa[m0], awbA, z);
    f4v ab = MFMA(fwa[m0], awbB, z);
    {
      float c0 = accHA[m0][0]*(aa[0]+fv[0])*0.35355339059f;
      float c1 = accHA[m0][1]*(aa[1]+fv[1])*0.35355339059f;
      float c2 = accHA[m0][2]*(aa[2]+fv[2])*0.35355339059f;
      float c3 = accHA[m0][3]*(aa[3]+fv[3])*0.35355339059f;
      ushort_t h0=f2bf(c0),h1=f2bf(c1),h2=f2bf(c2),h3=f2bf(c3);
      uint2 hv; hv.x=(unsigned)h0|((unsigned)h1<<16); hv.y=(unsigned)h2|((unsigned)h3<<16);
      *(uint2*)(smA + 2048 + ADR64(t, m0*32+g*8)) = hv;
      uint2 lv;
      lv.x = (unsigned)f2bf(c0-bf2f(h0)) | ((unsigned)f2bf(c1-bf2f(h1))<<16);
      lv.y = (unsigned)f2bf(c2-bf2f(h2)) | ((unsigned)f2bf(c3-bf2f(h3))<<16);
      *(uint2*)(smA + ADR64(t, m0*32+g*8)) = lv;
    }
    {
      float c0 = accHB[m0][0]*(ab[0]+fv[0])*0.35355339059f;
      float c1 = accHB[m0][1]*(ab[1]+fv[1])*0.35355339059f;
      float c2 = accHB[m0][2]*(ab[2]+fv[2])*0.35355339059f;
      float c3 = accHB[m0][3]*(ab[3]+fv[3])*0.35355339059f;
      ushort_t h0=f2bf(c0),h1=f2bf(c1),h2=f2bf(c2),h3=f2bf(c3);
      uint2 hv; hv.x=(unsigned)h0|((unsigned)h1<<16); hv.y=(unsigned)h2|((unsigned)h3<<16);
      *(uint2*)(smB + 2048 + ADR64(t, m0*32+g*8)) = hv;
      uint2 lv;
      lv.x = (unsigned)f2bf(c0-bf2f(h0)) | ((unsigned)f2bf(c1-bf2f(h1))<<16);
      lv.y = (unsigned)f2bf(c2-bf2f(h2)) | ((unsigned)f2bf(c3-bf2f(h3))<<16);
      *(uint2*)(smB + ADR64(t, m0*32+g*8)) = lv;
    }
  }
  FENCE();  // D

  // ---- S2 + softmax (both tiles) ----
  {
    s8v chA0 = *(const s8v*)(smA + 2048 + ADR64(t, g*16));
    s8v chA1 = *(const s8v*)(smA + 2048 + ADR64(t, 64+g*16));
    s8v clA0 = *(const s8v*)(smA + ADR64(t, g*16));
    s8v clA1 = *(const s8v*)(smA + ADR64(t, 64+g*16));
    s8v chB0 = *(const s8v*)(smB + 2048 + ADR64(t, g*16));
    s8v chB1 = *(const s8v*)(smB + 2048 + ADR64(t, 64+g*16));
    s8v clB0 = *(const s8v*)(smB + ADR64(t, g*16));
    s8v clB1 = *(const s8v*)(smB + ADR64(t, 64+g*16));
    f4v s2A = {0.f,0.f,0.f,0.f};
    s2A = MFMA(chA0, chA0, s2A); s2A = MFMA(chA1, chA1, s2A);
    s2A = MFMA(chA0, clA0, s2A); s2A = MFMA(chA1, clA1, s2A);
    s2A = MFMA(clA0, chA0, s2A); s2A = MFMA(clA1, chA1, s2A);
    f4v s2B = {0.f,0.f,0.f,0.f};
    s2B = MFMA(chB0, chB0, s2B); s2B = MFMA(chB1, chB1, s2B);
    s2B = MFMA(chB0, clB0, s2B); s2B = MFMA(chB1, clB1, s2B);
    s2B = MFMA(clB0, chB0, s2B); s2B = MFMA(clB1, chB1, s2B);
    float mA = fmaxf(fmaxf(s2A[0],s2A[1]), fmaxf(s2A[2],s2A[3]));
    mA = fmaxf(mA, __shfl_xor(mA,16)); mA = fmaxf(mA, __shfl_xor(mA,32));
    float mB = fmaxf(fmaxf(s2B[0],s2B[1]), fmaxf(s2B[2],s2B[3]));
    mB = fmaxf(mB, __shfl_xor(mB,16)); mB = fmaxf(mB, __shfl_xor(mB,32));
    float eA0=__expf(s2A[0]-mA), eA1=__expf(s2A[1]-mA), eA2=__expf(s2A[2]-mA), eA3=__expf(s2A[3]-mA);
    float eB0=__expf(s2B[0]-mB), eB1=__expf(s2B[1]-mB), eB2=__expf(s2B[2]-mB), eB3=__expf(s2B[3]-mB);
    float sA_ = eA0+eA1+eA2+eA3; sA_ += __shfl_xor(sA_,16); sA_ += __shfl_xor(sA_,32);
    float sB_ = eB0+eB1+eB2+eB3; sB_ += __shfl_xor(sB_,16); sB_ += __shfl_xor(sB_,32);
    float iA = 1.f/sA_, iB = 1.f/sB_;
    FENCE();  // D2
    st64(smA + ADR32(t, g*8), eA0*iA, eA1*iA, eA2*iA, eA3*iA);
    st64(smB + ADR32(t, g*8), eB0*iB, eB1*iB, eB2*iB, eB3*iB);
    uint2 zz; zz.x=0u; zz.y=0u;
    *(uint2*)(smA + ADR32(t, 32+g*8)) = zz;
    *(uint2*)(smB + ADR32(t, 32+g*8)) = zz;
  }
  FENCE();  // E

  // ---- CCH = H^T @ A_c^T ----
  {
    s8v acbA = *(const s8v*)(smA + ADR32(t, g*16));
    s8v acbB = *(const s8v*)(smB + ADR32(t, g*16));
    #pragma unroll
    for (int m0=0;m0<4;m0++){
      f4v z = {0.f,0.f,0.f,0.f};
      s8v aA = *(const s8v*)(smA + 4096 + ADR32(m0*16 + t, g*16));
      f4v ra = MFMA(aA, acbA, z);
      st64(smA + 2048 + ADR64(t, m0*32+g*8), ra[0],ra[1],ra[2],ra[3]);
      s8v aB = *(const s8v*)(smB + 4096 + ADR32(m0*16 + t, g*16));
      f4v rb = MFMA(aB, acbB, z);
      st64(smB + 2048 + ADR64(t, m0*32+g*8), rb[0],rb[1],rb[2],rb[3]);
    }
  }
  FENCE();  // F

  // ---- OUT phase ----
  s8v ccA0 = *(const s8v*)(smA + 2048 + ADR64(t, g*16));
  s8v ccA1 = *(const s8v*)(smA + 2048 + ADR64(t, 64+g*16));
  s8v ccB0 = *(const s8v*)(smB + 2048 + ADR64(t, g*16));
  s8v ccB1 = *(const s8v*)(smB + 2048 + ADR64(t, 64+g*16));
  FENCE();  // F2
  const float* fmpA = fm_src + (size_t)tileA*DD;
  const float* fmpB = fm_src + (size_t)tileB*DD;
  const float* fsp = fsg + b*DD;
  const int frofs = t*8 + (g>>1)*128 + (g&1)*4;
  const ushort_t* xfrA = (const ushort_t*)cusrc_ + (size_t)tileA*4096 + frofs;
  const ushort_t* xfrB = (const ushort_t*)cusrc_ + (size_t)tileB*4096 + frofs;
  ushort_t* ofrA = cudst + (size_t)tileA*4096 + frofs;
  ushort_t* ofrB = cudst + (size_t)tileB*4096 + frofs;
  const float* xfA = (const float*)cusrc_ + (size_t)tileA*4096 + t*DD;
  const float* xfB = (const float*)cusrc_ + (size_t)tileB*4096 + t*DD;
  #pragma unroll
  for (int m0=0;m0<16;m0++){
    s8v a0 = *(const s8v*)(uccf + (((m0<<1)  )<<9) + (lane<<3));
    s8v a1 = *(const s8v*)(uccf + (((m0<<1)+1)<<9) + (lane<<3));
    f4v accA = {0.f,0.f,0.f,0.f};
    accA = MFMA(a0, ccA0, accA); accA = MFMA(a1, ccA1, accA);
    f4v accB = {0.f,0.f,0.f,0.f};
    accB = MFMA(a0, ccB0, accB); accB = MFMA(a1, ccB1, accB);
    const int dq = m0*16 + g*4;
    const int fi = (m0>>1)*512 + (m0&1)*256;
    f4v ub  = *(const f4v*)(uccb + dq);
    f4v fvv = *(const f4v*)(fsp + dq);
    // tile A
    {
      f4v fmv = *(const f4v*)(fmpA + dq);
      float xr0,xr1,xr2,xr3;
      if (FIRST){
        f4v xv = *(const f4v*)(xfA + dq);
        xr0=xv[0]; xr1=xv[1]; xr2=xv[2]; xr3=xv[3];
      } else {
        uint2 xv = *(const uint2*)(xfrA + fi);
        xr0=bf2f((ushort_t)(xv.x&0xffffu)); xr1=bf2f((ushort_t)(xv.x>>16));
        xr2=bf2f((ushort_t)(xv.y&0xffffu)); xr3=bf2f((ushort_t)(xv.y>>16));
      }
      float o0 = accA[0]+ub[0]+xr0 + fmv[0]*__builtin_amdgcn_rcpf(1.f+__expf(-fmv[0]*fvv[0]));
      float o1 = accA[1]+ub[1]+xr1 + fmv[1]*__builtin_amdgcn_rcpf(1.f+__expf(-fmv[1]*fvv[1]));
      float o2 = accA[2]+ub[2]+xr2 + fmv[2]*__builtin_amdgcn_rcpf(1.f+__expf(-fmv[2]*fvv[2]));
      float o3 = accA[3]+ub[3]+xr3 + fmv[3]*__builtin_amdgcn_rcpf(1.f+__expf(-fmv[3]*fvv[3]));
      uint2 ov; ov.x=(unsigned)f2bf(o0)|((unsigned)f2bf(o1)<<16);
      ov.y=(unsigned)f2bf(o2)|((unsigned)f2bf(o3)<<16);
      *(uint2*)(ofrA + fi) = ov;
      *(uint2*)(smA + (t<<9) + ((dq*2) ^ ((t&15)<<3))) = ov;
    }
    // tile B
    {
      f4v fmv = *(const f4v*)(fmpB + dq);
      float xr0,xr1,xr2,xr3;
      if (FIRST){
        f4v xv = *(const f4v*)(xfB + dq);
        xr0=xv[0]; xr1=xv[1]; xr2=xv[2]; xr3=xv[3];
      } else {
        uint2 xv = *(const uint2*)(xfrB + fi);
        xr0=bf2f((ushort_t)(xv.x&0xffffu)); xr1=bf2f((ushort_t)(xv.x>>16));
        xr2=bf2f((ushort_t)(xv.y&0xffffu)); xr3=bf2f((ushort_t)(xv.y>>16));
      }
      float o0 = accB[0]+ub[0]+xr0 + fmv[0]*__builtin_amdgcn_rcpf(1.f+__expf(-fmv[0]*fvv[0]));
      float o1 = accB[1]+ub[1]+xr1 + fmv[1]*__builtin_amdgcn_rcpf(1.f+__expf(-fmv[1]*fvv[1]));
      float o2 = accB[2]+ub[2]+xr2 + fmv[2]*__builtin_amdgcn_rcpf(1.f+__expf(-fmv[2]*fvv[2]));
      float o3 = accB[3]+ub[3]+xr3 + fmv[3]*__builtin_amdgcn_rcpf(1.f+__expf(-fmv[3]*fvv[3]));
      uint2 ov; ov.x=(unsigned)f2bf(o0)|((unsigned)f2bf(o1)<<16);
      ov.y=(unsigned)f2bf(o2)|((unsigned)f2bf(o3)<<16);
      *(uint2*)(ofrB + fi) = ov;
      *(uint2*)(smB + (t<<9) + ((dq*2) ^ ((t&15)<<3))) = ov;
    }
  }
  FENCE();  // G

  // ---- fused meank for both tiles ----
  {
    const int d0 = lane*4;
    float a0=0.f,a1=0.f,a2=0.f,a3=0.f;
    float b0=0.f,b1=0.f,b2=0.f,b3=0.f;
    #pragma unroll
    for (int tt=0;tt<TT;tt++){
      uint2 v = *(const uint2*)(smA + (tt<<9) + ((d0*2) ^ ((tt&15)<<3)));
      a0 += bf2f((ushort_t)(v.x&0xffffu)); a1 += bf2f((ushort_t)(v.x>>16));
      a2 += bf2f((ushort_t)(v.y&0xffffu)); a3 += bf2f((ushort_t)(v.y>>16));
      uint2 w = *(const uint2*)(smB + (tt<<9) + ((d0*2) ^ ((tt&15)<<3)));
      b0 += bf2f((ushort_t)(w.x&0xffffu)); b1 += bf2f((ushort_t)(w.x>>16));
      b2 += bf2f((ushort_t)(w.y&0xffffu)); b3 += bf2f((ushort_t)(w.y>>16));
    }
    f4v oa = {a0*0.0625f, a1*0.0625f, a2*0.0625f, a3*0.0625f};
    *(f4v*)(cm + (size_t)tileA*DD + d0) = oa;
    f4v ob = {b0*0.0625f, b1*0.0625f, b2*0.0625f, b3*0.0625f};
    *(f4v*)(cm + (size_t)tileB*DD + d0) = ob;
  }
}

// =====================================================================
// BOUNDARY UNIT (fp32 VALU; tiny)
// =====================================================================
__global__ __launch_bounds__(256)
void bnd1_kernel(const float* __restrict__ fb, const float* __restrict__ f_w,
                 const float* __restrict__ f_s, const float* __restrict__ kb,
                 const float* __restrict__ bWqT, const float* __restrict__ bbq,
                 float* __restrict__ fbq)
{
  int blk = blockIdx.x; int b = blk / LL, l = blk % LL;
  int d = threadIdx.x;
  __shared__ float fbrow[DD];
  __shared__ float qrow[DD];
  __shared__ float smx[32];
  fbrow[d] = fb[(size_t)(b*LL+l)*DD + d];
  __syncthreads();
  float q = bbq[d];
  for (int e=0;e<DD;e++) q += fbrow[e]*bWqT[(size_t)e*DD+d];
  qrow[d]=q;
  __syncthreads();
  if (d < NWW){
    float s=0.f; const float* kr = kb + (size_t)(b*NWW+d)*DD;
    for (int e=0;e<DD;e++) s += qrow[e]*kr[e];
    smx[d] = s*(1.0f/16.0f);
  }
  __syncthreads();
  if (d==0){
    float m2=-3.0e38f;
    for(int n=0;n<NWW;n++) m2=fmaxf(m2,smx[n]);
    float su=0.f;
    for(int n=0;n<NWW;n++){ float e=__expf(smx[n]-m2); smx[n]=e; su+=e; }
    float iv=1.f/su;
    for(int n=0;n<NWW;n++) smx[n]*=iv;
  }
  __syncthreads();
  float acc=0.f;
  for (int n=0;n<NWW;n++) acc += smx[n]*f_w[(size_t)(b*NWW+n)*DD+d];
  fbq[(size_t)(b*LL+l)*DD+d] = fbrow[d]*(acc + f_s[b*DD+d]);
}

__global__ __launch_bounds__(256)
void bnd2_kernel(const float* __restrict__ fbq, const float* __restrict__ fb,
                 const float* __restrict__ fm, const float* __restrict__ f_s,
                 float* __restrict__ bu_out)
{
  int blk = blockIdx.x; int b = blk/LL, l = blk%LL;
  int d = threadIdx.x;
  __shared__ float Sl[DD];
  __shared__ float aw[LL];
  Sl[d] = fbq[(size_t)(b*LL+l)*DD + d];
  __syncthreads();
  if (d < LL){
    float s=0.f; const float* fr = fbq + (size_t)(b*LL+d)*DD;
    const f4v* s4 = (const f4v*)Sl; const f4v* f4p = (const f4v*)fr;
    for (int e=0;e<DD/4;e++){
      f4v a=s4[e], c=f4p[e];
      s += a[0]*c[0]+a[1]*c[1]+a[2]*c[2]+a[3]*c[3];
    }
    aw[d] = s*(1.0f/16.0f);
  }
  __syncthreads();
  if (d==0){
    float m2=-3.0e38f;
    for(int n=0;n<LL;n++) m2=fmaxf(m2,aw[n]);
    float su=0.f;
    for(int n=0;n<LL;n++){ float e=__expf(aw[n]-m2); aw[n]=e; su+=e; }
    float iv=1.f/su;
    for(int n=0;n<LL;n++) aw[n]*=iv;
  }
  __syncthreads();
  float fsd = f_s[b*DD+d];
  const float* fmrow = fm + ((size_t)(b*LL+l)*LL)*DD + d;
  float acc=0.f;
  for (int m=0;m<LL;m++){
    float a  = aw[m];
    float fbv= fb[(size_t)(b*LL+m)*DD+d];
    float fmv= fmrow[(size_t)m*DD];
    float gm = 1.f/(1.f+__expf(-fmv*fsd));
    acc += a*(fbv + gm*fmv);
  }
  bu_out[(size_t)(b*LL+l)*DD+d] = acc + fb[(size_t)(b*LL+l)*DD+d];
}

// =====================================================================
// MOMENT UNIT — writes mu directly into d_out (fp32)
// =====================================================================
__global__ __launch_bounds__(256)
void moment_kernel(const float* __restrict__ cm, const float* __restrict__ bu,
                   const float* __restrict__ mu_in, float* __restrict__ mu_out,
                   const float* __restrict__ wbT, const float* __restrict__ wcT,
                   const float* __restrict__ mfbb, const float* __restrict__ mfcb)
{
  int blk = blockIdx.x;
  int oh = blk & 1; int bm = blk>>1; int b = bm/LL, m = bm%LL;
  int d = threadIdx.x;
  const int ob = oh*24;
  float accB[24], accC[24];
  #pragma unroll
  for (int o=0;o<24;o++){accB[o]=0.f;accC[o]=0.f;}
  for (int i=0;i<LL;i++){
    float bv = bu[(size_t)(b*LL+i)*DD+d];
    float cv = cm[((size_t)(b*LL+i)*LL+m)*DD+d];
    const float* wb = wbT + i*LL + ob;
    const float* wc = wcT + i*LL + ob;
    #pragma unroll
    for (int o=0;o<24;o+=4){
      f4v w1 = *(const f4v*)(wb+o);
      f4v w2 = *(const f4v*)(wc+o);
      accB[o  ]+=w1[0]*bv; accB[o+1]+=w1[1]*bv; accB[o+2]+=w1[2]*bv; accB[o+3]+=w1[3]*bv;
      accC[o  ]+=w2[0]*cv; accC[o+1]+=w2[1]*cv; accC[o+2]+=w2[2]*cv; accC[o+3]+=w2[3]*cv;
    }
  }
  float bum = bu[(size_t)(b*LL+m)*DD+d];
  #pragma unroll
  for (int o=0;o<24;o++){
    int oo = ob+o;
    size_t oi = ((size_t)(b*LL+oo)*LL+m)*DD + d;
    mu_out[oi] = accB[o]*bum + mfbb[oo] + accC[o] + mfcb[oo] + mu_in[oi];
  }
}

// =====================================================================
// PREP1
// =====================================================================
__global__ __launch_bounds__(256)
void prep1_kernel(const float* __restrict__ f_w, const float* __restrict__ f_s,
                  const float* __restrict__ bWq, const float* __restrict__ bWk,
                  const float* __restrict__ bbk,
                  const float* __restrict__ dcw_w, const float* __restrict__ dcw_b,
                  const float* __restrict__ dcs_w, const float* __restrict__ dcs_b,
                  const float* __restrict__ dcc_w, const float* __restrict__ cWq,
                  const float* __restrict__ ucc_w,
                  const float* __restrict__ mfb_w, const float* __restrict__ mfc_w,
                  float* __restrict__ kb, float* __restrict__ fwh,
                  float* __restrict__ fsh, float* __restrict__ bWqT,
                  ushort_t* __restrict__ dccf, ushort_t* __restrict__ cwqf,
                  ushort_t* __restrict__ uccf,
                  float* __restrict__ wbT, float* __restrict__ wcT)
{
  const int S0=20480, S1=5120, S2=256, S3=65536, S4=16384, S5=4096, S6=16384, S7=2304;
  const int TOT = S0+S1+S2+S3+S4+S5+S6+S7;
  int id = blockIdx.x*256 + threadIdx.x;
  int nth = gridDim.x*256;
  for (int x=id; x<TOT; x+=nth){
    int y=x;
    if (y < S0){
      int b=y/(NWW*DD); int r=y%(NWW*DD); int n=r/DD, dd2=r%DD;
      float s=bbk[dd2];
      const float* fr=f_w+(size_t)(b*NWW+n)*DD; const float* wr=bWk+(size_t)dd2*DD;
      for(int e=0;e<DD;e++) s+=fr[e]*wr[e];
      kb[y]=s; continue; }
    y-=S0;
    if (y < S1){
      int b=y/(NWW*DLL); int r=y%(NWW*DLL); int n=r/DLL, dl=r%DLL;
      float s=dcw_b[dl];
      const float* fr=f_w+(size_t)(b*NWW+n)*DD; const float* wr=dcw_w+(size_t)dl*DD;
      for(int e=0;e<DD;e++) s+=fr[e]*wr[e];
      fwh[y]=s; continue; }
    y-=S1;
    if (y < S2){
      int b=y/DLL, dl=y%DLL;
      float s=dcs_b[dl];
      const float* fr=f_s+(size_t)b*DD; const float* wr=dcs_w+(size_t)dl*DD;
      for(int e=0;e<DD;e++) s+=fr[e]*wr[e];
      fsh[y]=s; continue; }
    y-=S2;
    if (y < S3){ int e=y/DD, dd2=y%DD; bWqT[y] = bWq[(size_t)dd2*DD+e]; continue; }
    y-=S3;
    if (y < S4){
      int j=y&7, ln=(y>>3)&63, kk=(y>>9)&7, m0=y>>12;
      int mm=m0*16+(ln&15), k=kk*32+((ln>>4)<<3)+j;
      dccf[y]=f2bf(dcc_w[(size_t)mm*DD+k]); continue; }
    y-=S4;
    if (y < S5){
      int j=y&7, ln=(y>>3)&63, kk=(y>>9)&1, m0=y>>10;
      int mm=m0*16+(ln&15), k=kk*32+((ln>>4)<<3)+j;
      cwqf[y]=f2bf(cWq[(size_t)mm*DLL+k]); continue; }
    y-=S5;
    if (y < S6){
      int j=y&7, ln=(y>>3)&63, kk=(y>>9)&1, m0=y>>10;
      int mm=m0*16+(ln&15), k=kk*32+((ln>>4)<<3)+j;
      uccf[y]=f2bf(ucc_w[(size_t)mm*DLL+k]); continue; }
    y-=S6;
    { int i=y/LL, o=y%LL; wbT[y]=mfb_w[(size_t)o*LL+i]; wcT[y]=mfc_w[(size_t)o*LL+i]; }
  }
}

// =====================================================================
// PREP2
// =====================================================================
__global__ __launch_bounds__(256)
void prep2_kernel(const float* __restrict__ fwh, const float* __restrict__ cWk,
                  const float* __restrict__ cbk,
                  ushort_t* __restrict__ kcf, ushort_t* __restrict__ fwhtf)
{
  const int S0 = BB*2048, S1 = BB*2048;
  int id = blockIdx.x*256+threadIdx.x; int nth=gridDim.x*256;
  for (int x=id; x<S0+S1; x+=nth){
    int y=x;
    if (y < S0){
      int b=y>>11; int z=y&2047;
      int j=z&7, ln=(z>>3)&63, kk=(z>>9)&1, m0=z>>10;
      int n=m0*16+(ln&15), k=kk*32+((ln>>4)<<3)+j;
      float v=0.f;
      if (n<NWW){
        float s=cbk[k];
        const float* fr=fwh+(size_t)(b*NWW+n)*DLL; const float* wr=cWk+(size_t)k*DLL;
        for(int e=0;e<DLL;e++) s+=fr[e]*wr[e];
        v=s*0.125f;
      }
      kcf[y]=f2bf(v); continue; }
    y-=S0;
    {
      int b=y>>11; int z=y&2047;
      int j=z&7, ln=(z>>3)&63, m0=z>>9;
      int dl=m0*16+(ln&15), n=((ln>>4)<<3)+j;
      float v = (n<NWW)? fwh[(size_t)(b*NWW+n)*DLL+dl] : 0.f;
      fwhtf[y]=f2bf(v);
    }
  }
}

// =====================================================================
extern "C" void kernel_launch(void* const* d_in, const int* in_sizes, int n_in,
                              void* d_out, int out_size, void* d_ws, size_t ws_size,
                              hipStream_t stream)
{
  (void)in_sizes; (void)n_in; (void)out_size; (void)ws_size;
  const float* f_c  = (const float*)d_in[0];
  const float* f_m  = (const float*)d_in[1];
  const float* f_b  = (const float*)d_in[2];
  const float* f_w  = (const float*)d_in[3];
  const float* f_s  = (const float*)d_in[4];
  const float* bWq  = (const float*)d_in[5];
  const float* bbq  = (const float*)d_in[6];
  const float* bWk  = (const float*)d_in[7];
  const float* bbk  = (const float*)d_in[8];
  const float* cWq  = (const float*)d_in[9];
  const float* cbq  = (const float*)d_in[10];
  const float* cWk  = (const float*)d_in[11];
  const float* cbk  = (const float*)d_in[12];
  const float* dcc_w= (const float*)d_in[13];
  const float* dcc_b= (const float*)d_in[14];
  const float* dcw_w= (const float*)d_in[15];
  const float* dcw_b= (const float*)d_in[16];
  const float* dcs_w= (const float*)d_in[17];
  const float* dcs_b= (const float*)d_in[18];
  const float* ucc_w= (const float*)d_in[19];
  const float* ucc_b= (const float*)d_in[20];
  const float* mfb_w= (const float*)d_in[21];
  const float* mfb_b= (const float*)d_in[22];
  const float* mfc_w= (const float*)d_in[23];
  const float* mfc_b= (const float*)d_in[24];

  char* ws = (char*)d_ws;
  ushort_t* cu = (ushort_t*)(ws+OFF_CU);
  float* cmr  = (float*)(ws+OFF_CM);
  float* bu0  = (float*)(ws+OFF_BU0);
  float* bu1  = (float*)(ws+OFF_BU1);
  float* fbq  = (float*)(ws+OFF_FBQ);
  float* fwh  = (float*)(ws+OFF_FWH);
  float* fsh  = (float*)(ws+OFF_FSH);
  float* kb   = (float*)(ws+OFF_KB);
  float* bWqT = (float*)(ws+OFF_BWQT);
  float* wbT  = (float*)(ws+OFF_WBT);
  float* wcT  = (float*)(ws+OFF_WCT);
  ushort_t* dccf = (ushort_t*)(ws+OFF_DCCF);
  ushort_t* cwqf = (ushort_t*)(ws+OFF_CWQF);
  ushort_t* uccf = (ushort_t*)(ws+OFF_UCCF);
  ushort_t* kcf  = (ushort_t*)(ws+OFF_KCF);
  ushort_t* fwhtf= (ushort_t*)(ws+OFF_FWHTF);

  float* mu = (float*)d_out;
  float* out_bu = (float*)d_out + 2359296;

  prep1_kernel<<<128,256,0,stream>>>(f_w,f_s,bWq,bWk,bbk,dcw_w,dcw_b,dcs_w,dcs_b,
                                     dcc_w,cWq,ucc_w,mfb_w,mfc_w,
                                     kb,fwh,fsh,bWqT,dccf,cwqf,uccf,wbT,wcT);
  prep2_kernel<<<32,256,0,stream>>>(fwh,cWk,cbk,kcf,fwhtf);

  float* bu_cur = nullptr;
  for (int it=0; it<3; ++it){
    const float* fmsrc = (it==0)? f_m : mu;
    if (it==0)
      content_kernel<1><<<2304,128,0,stream>>>(f_c, cu, cmr, fmsrc, f_s, fsh, dcc_b, cbq, ucc_b,
                                               dccf,cwqf,uccf,kcf,fwhtf);
    else
      content_kernel<0><<<2304,128,0,stream>>>(cu, cu, cmr, fmsrc, f_s, fsh, dcc_b, cbq, ucc_b,
                                               dccf,cwqf,uccf,kcf,fwhtf);
    const float* fbsrc = (it==0)? f_b : bu_cur;
    float* bunew = (it==2)? out_bu : ((it==0)? bu0 : ((bu_cur==bu0)? bu1 : bu0));
    bnd1_kernel<<<192,256,0,stream>>>(fbsrc, f_w, f_s, kb, bWqT, bbq, fbq);
    bnd2_kernel<<<192,256,0,stream>>>(fbq, fbsrc, fmsrc, f_s, bunew);
    moment_kernel<<<384,256,0,stream>>>(cmr, bunew, fmsrc, mu, wbT, wcT, mfb_b, mfc_b);
    bu_cur = bunew;
  }
}

// Round 13
// 395.068 us; speedup vs baseline: 1.2079x; 1.2079x over previous
//
#include <hip/hip_runtime.h>

#define BB 4
#define LL 48
#define TT 16
#define NWW 20
#define DD 256
#define DLL 64

typedef __attribute__((ext_vector_type(8))) short s8v;
typedef __attribute__((ext_vector_type(4))) float f4v;
typedef unsigned short ushort_t;

#define FENCE() asm volatile("" ::: "memory")

// ---- ws layout (bytes) ----
#define OFF_CU     0ull           // bf16 cu state (FRAGMENT order): 75,497,472
#define OFF_CM     75497472ull
#define OFF_BU0    84934656ull
#define OFF_BU1    85131264ull
#define OFF_FBQ    85327872ull
#define OFF_FWH    85524480ull
#define OFF_FSH    85544960ull
#define OFF_KB     85545984ull
#define OFF_BWQT   85627904ull
#define OFF_WBT    85890048ull
#define OFF_WCT    85899264ull
#define OFF_DCCF   85908480ull
#define OFF_CWQF   85941248ull
#define OFF_UCCF   85949440ull
#define OFF_KCF    85982208ull
#define OFF_FWHTF  85998592ull

static __device__ __forceinline__ ushort_t f2bf(float f){
  unsigned u = __float_as_uint(f);
  return (ushort_t)((u + 0x7FFFu + ((u>>16)&1u)) >> 16);
}
static __device__ __forceinline__ float bf2f(ushort_t h){
  return __uint_as_float(((unsigned)h)<<16);
}
static __device__ __forceinline__ void st64(void* p, float a, float b, float c, float d){
  uint2 v; v.x = (unsigned)f2bf(a) | ((unsigned)f2bf(b)<<16);
  v.y = (unsigned)f2bf(c) | ((unsigned)f2bf(d)<<16);
  *(uint2*)p = v;
}

#define ADR64(row, cb) (((row)<<7) + ((cb) ^ (((row)&7)<<4)))
#define ADR32(row, cb) (((row)<<6) + ((cb) ^ (((row)&3)<<4)))

#define MFMA(a,b,c) __builtin_amdgcn_mfma_f32_16x16x32_bf16((a),(b),(c),0,0,0)

// =====================================================================
// CONTENT UNIT: 2 independent waves per block, one (b,l,m) tile per
// wave, private 6 KB LDS slice, no hardware barriers. 13 blocks/CU ->
// 26 resident tile-streams (throughput ~ streams; R11/R12 data).
// LDS overlay per tile (6144 B):
//   0..2048    : HLDS -> AWLDS(1KB) -> CQLO -> ACLDS(1KB + 1KB zeros)
//   2048..4096 : QLDS -> CQHI -> CCHLDS
//   4096..6144 : HT [64][16] ushorts (NO k-pad: B operand is zero for
//                k>=16, so A reads for g>=2 alias g&1 -> garbage-safe)
// Fused T-mean via shfl_xor tree over t-lanes (no LDS staging).
// cu in FRAGMENT ORDER (see R11).
// =====================================================================
template<int FIRST>
__global__ __launch_bounds__(128)
void content_kernel(const void* cusrc_, ushort_t* cudst, float* __restrict__ cm,
                    const float* __restrict__ fm_src, const float* __restrict__ fsg,
                    const float* __restrict__ fsh, const float* __restrict__ dccb,
                    const float* __restrict__ cbq, const float* __restrict__ uccb,
                    const ushort_t* __restrict__ dccf, const ushort_t* __restrict__ cwqf,
                    const ushort_t* __restrict__ uccf, const ushort_t* __restrict__ kcf,
                    const ushort_t* __restrict__ fwhtf)
{
  __shared__ __align__(16) char sm_all[2][6144];
  const int wid = threadIdx.x >> 6;
  const int lane = threadIdx.x & 63;
  char* sm = sm_all[wid];
  const int t = lane & 15, g = lane >> 4;
  const int tile = blockIdx.x*2 + wid;
  const int b = tile / (LL*LL);

  // ---- X B-fragments: X[t][k], k = kk*32+g*8+j ----
  s8v xb[8];
  if (FIRST){
    const float* xp = (const float*)cusrc_ + (size_t)tile*4096 + t*DD + g*8;
    #pragma unroll
    for (int kk=0;kk<8;kk++){
      f4v lo = *(const f4v*)(xp + kk*32);
      f4v hi = *(const f4v*)(xp + kk*32 + 4);
      s8v v;
      v[0]=(short)f2bf(lo[0]); v[1]=(short)f2bf(lo[1]);
      v[2]=(short)f2bf(lo[2]); v[3]=(short)f2bf(lo[3]);
      v[4]=(short)f2bf(hi[0]); v[5]=(short)f2bf(hi[1]);
      v[6]=(short)f2bf(hi[2]); v[7]=(short)f2bf(hi[3]);
      xb[kk]=v;
    }
  } else {
    const ushort_t* xp = (const ushort_t*)cusrc_ + (size_t)tile*4096 + lane*8;
    #pragma unroll
    for (int kk=0;kk<8;kk++) xb[kk] = *(const s8v*)(xp + kk*512);
  }

  // ---- H^T = dcc_w @ X^T + dcc_b ----
  f4v accH[4];
  {
    f4v z = {0.f,0.f,0.f,0.f};
    accH[0]=z; accH[1]=z; accH[2]=z; accH[3]=z;
  }
  #pragma unroll
  for (int kk=0;kk<8;kk++){
    #pragma unroll
    for (int m0=0;m0<4;m0++){
      s8v a = *(const s8v*)(dccf + (((m0<<3)+kk)<<9) + (lane<<3));
      accH[m0] = MFMA(a, xb[kk], accH[m0]);
    }
  }
  // hoisted A-fragments for the Q phase
  s8v cwa[8];
  #pragma unroll
  for (int i=0;i<8;i++) cwa[i] = *(const s8v*)(cwqf + (i<<9) + (lane<<3));
  #pragma unroll
  for (int m0=0;m0<4;m0++){
    f4v acc = accH[m0];
    f4v bi = *(const f4v*)(dccb + m0*16 + g*4);
    acc[0]+=bi[0]; acc[1]+=bi[1]; acc[2]+=bi[2]; acc[3]+=bi[3];
    accH[m0]=acc;
    st64(sm + ADR64(t, m0*32 + g*8), acc[0],acc[1],acc[2],acc[3]);   // HLDS [t][dl]
    #pragma unroll
    for (int r=0;r<4;r++)                                            // HT [dl][t], 32B rows
      *(ushort_t*)(sm + 4096 + (m0*16 + g*4 + r)*32 + t*2) = f2bf(acc[r]);
  }
  FENCE();  // A

  // ---- q^T = cWq @ H^T + cbq ----
  s8v hb0 = *(const s8v*)(sm + ADR64(t, g*16));
  s8v hb1 = *(const s8v*)(sm + ADR64(t, 64 + g*16));
  #pragma unroll
  for (int m0=0;m0<4;m0++){
    f4v acc = {0.f,0.f,0.f,0.f};
    acc = MFMA(cwa[m0*2  ], hb0, acc);
    acc = MFMA(cwa[m0*2+1], hb1, acc);
    f4v bi = *(const f4v*)(cbq + m0*16 + g*4);
    st64(sm + 2048 + ADR64(t, m0*32 + g*8),
         acc[0]+bi[0], acc[1]+bi[1], acc[2]+bi[2], acc[3]+bi[3]);    // QLDS
  }
  s8v kca[4];
  #pragma unroll
  for (int i=0;i<4;i++) kca[i] = *(const s8v*)(kcf + (b<<11) + (i<<9) + (lane<<3));
  FENCE();  // B

  // ---- s^T = (kc/8) @ q^T ----
  s8v qb0 = *(const s8v*)(sm + 2048 + ADR64(t, g*16));
  s8v qb1 = *(const s8v*)(sm + 2048 + ADR64(t, 64 + g*16));
  f4v sA[2];
  #pragma unroll
  for (int m0=0;m0<2;m0++){
    f4v acc = {0.f,0.f,0.f,0.f};
    acc = MFMA(kca[m0*2  ], qb0, acc);
    acc = MFMA(kca[m0*2+1], qb1, acc);
    sA[m0]=acc;
  }
  // softmax over n
  float mx = -3.0e38f;
  #pragma unroll
  for (int m0=0;m0<2;m0++){
    #pragma unroll
    for (int r=0;r<4;r++){
      int n = m0*16 + g*4 + r;
      if (n < NWW) mx = fmaxf(mx, sA[m0][r]);
    }
  }
  mx = fmaxf(mx, __shfl_xor(mx, 16));
  mx = fmaxf(mx, __shfl_xor(mx, 32));
  float ex[8]; float sum = 0.f;
  #pragma unroll
  for (int m0=0;m0<2;m0++){
    #pragma unroll
    for (int r=0;r<4;r++){
      int n = m0*16 + g*4 + r;
      float e = (n < NWW) ? __expf(sA[m0][r]-mx) : 0.f;
      ex[m0*4+r]=e; sum+=e;
    }
  }
  sum += __shfl_xor(sum,16);
  sum += __shfl_xor(sum,32);
  float inv = 1.f/sum;
  #pragma unroll
  for (int m0=0;m0<2;m0++)
    st64(sm + ADR32(t, m0*32 + g*8),
         ex[m0*4]*inv, ex[m0*4+1]*inv, ex[m0*4+2]*inv, ex[m0*4+3]*inv); // AWLDS @0
  s8v fwa[4];
  #pragma unroll
  for (int i=0;i<4;i++) fwa[i] = *(const s8v*)(fwhtf + (b<<11) + (i<<9) + (lane<<3));
  FENCE();  // C

  // ---- f_caq^T = fwh^T @ aw^T ; f_cq (x 8^-0.5, hi/lo split) ----
  s8v awb = *(const s8v*)(sm + ADR32(t, g*16));
  FENCE();  // C2
  #pragma unroll
  for (int m0=0;m0<4;m0++){
    f4v z = {0.f,0.f,0.f,0.f};
    f4v acc = MFMA(fwa[m0], awb, z);
    f4v fv = *(const f4v*)(fsh + b*DLL + m0*16 + g*4);
    float cq0 = accH[m0][0]*(acc[0]+fv[0])*0.35355339059f;
    float cq1 = accH[m0][1]*(acc[1]+fv[1])*0.35355339059f;
    float cq2 = accH[m0][2]*(acc[2]+fv[2])*0.35355339059f;
    float cq3 = accH[m0][3]*(acc[3]+fv[3])*0.35355339059f;
    ushort_t h0=f2bf(cq0),h1=f2bf(cq1),h2=f2bf(cq2),h3=f2bf(cq3);
    uint2 hv; hv.x=(unsigned)h0|((unsigned)h1<<16); hv.y=(unsigned)h2|((unsigned)h3<<16);
    *(uint2*)(sm + 2048 + ADR64(t, m0*32+g*8)) = hv;                 // CQHI @2048
    uint2 lv;
    lv.x = (unsigned)f2bf(cq0-bf2f(h0)) | ((unsigned)f2bf(cq1-bf2f(h1))<<16);
    lv.y = (unsigned)f2bf(cq2-bf2f(h2)) | ((unsigned)f2bf(cq3-bf2f(h3))<<16);
    *(uint2*)(sm + ADR64(t, m0*32+g*8)) = lv;                        // CQLO @0
  }
  FENCE();  // D

  // ---- S2 = f_cq f_cq^T (hh+hl+lh; symmetric) ----
  s8v ch0 = *(const s8v*)(sm + 2048 + ADR64(t, g*16));
  s8v ch1 = *(const s8v*)(sm + 2048 + ADR64(t, 64+g*16));
  s8v cl0 = *(const s8v*)(sm + ADR64(t, g*16));
  s8v cl1 = *(const s8v*)(sm + ADR64(t, 64+g*16));
  f4v s2 = {0.f,0.f,0.f,0.f};
  s2 = MFMA(ch0, ch0, s2); s2 = MFMA(ch1, ch1, s2);
  s2 = MFMA(ch0, cl0, s2); s2 = MFMA(ch1, cl1, s2);
  s2 = MFMA(cl0, ch0, s2); s2 = MFMA(cl1, ch1, s2);
  float mx2 = fmaxf(fmaxf(s2[0],s2[1]), fmaxf(s2[2],s2[3]));
  mx2 = fmaxf(mx2, __shfl_xor(mx2,16));
  mx2 = fmaxf(mx2, __shfl_xor(mx2,32));
  float e0=__expf(s2[0]-mx2), e1=__expf(s2[1]-mx2), e2=__expf(s2[2]-mx2), e3=__expf(s2[3]-mx2);
  float su = e0+e1+e2+e3;
  su += __shfl_xor(su,16);
  su += __shfl_xor(su,32);
  float inv2 = 1.f/su;
  FENCE();  // D2
  st64(sm + ADR32(t, g*8), e0*inv2, e1*inv2, e2*inv2, e3*inv2);      // ACLDS @0
  { uint2 zz; zz.x=0u; zz.y=0u; *(uint2*)(sm + ADR32(t, 32+g*8)) = zz; }
  FENCE();  // E

  // ---- f_cc_hat^T = H^T @ A_c^T (A from HT [64][16]; g>=2 alias g&1,
  //      garbage-safe since ACLDS k>=16 is zero) ----
  s8v acb = *(const s8v*)(sm + ADR32(t, g*16));
  #pragma unroll
  for (int m0=0;m0<4;m0++){
    s8v a = *(const s8v*)(sm + 4096 + (m0*16 + t)*32 + (g&1)*16);
    f4v z = {0.f,0.f,0.f,0.f};
    f4v acc = MFMA(a, acb, z);
    st64(sm + 2048 + ADR64(t, m0*32+g*8), acc[0],acc[1],acc[2],acc[3]); // CCHLDS
  }
  FENCE();  // F

  // ---- f_cc^T = ucc_w @ f_cc_hat^T ; out = f_cc + fc + sigmoid(fm*fs)*fm
  //      + fused T-mean via shfl_xor tree over t-lanes ----
  s8v cc0 = *(const s8v*)(sm + 2048 + ADR64(t, g*16));
  s8v cc1 = *(const s8v*)(sm + 2048 + ADR64(t, 64+g*16));
  const float* fmp = fm_src + (size_t)tile*DD;
  const float* fsp = fsg + b*DD;
  const int frofs = t*8 + (g>>1)*128 + (g&1)*4;
  const ushort_t* xfr = (const ushort_t*)cusrc_ + (size_t)tile*4096 + frofs;
  ushort_t* ofr = cudst + (size_t)tile*4096 + frofs;
  const float* xf = (const float*)cusrc_ + (size_t)tile*4096 + t*DD;  // FIRST=1 path
  float* cmp = cm + (size_t)tile*DD;
  #pragma unroll
  for (int m0=0;m0<16;m0++){
    f4v acc = {0.f,0.f,0.f,0.f};
    s8v a0 = *(const s8v*)(uccf + (((m0<<1)  )<<9) + (lane<<3));
    s8v a1 = *(const s8v*)(uccf + (((m0<<1)+1)<<9) + (lane<<3));
    acc = MFMA(a0, cc0, acc);
    acc = MFMA(a1, cc1, acc);
    const int dq = m0*16 + g*4;
    const int fi = (m0>>1)*512 + (m0&1)*256;
    f4v ub  = *(const f4v*)(uccb + dq);
    f4v fmv = *(const f4v*)(fmp + dq);
    f4v fvv = *(const f4v*)(fsp + dq);
    float xr0,xr1,xr2,xr3;
    if (FIRST){
      f4v xv = *(const f4v*)(xf + dq);
      xr0=xv[0]; xr1=xv[1]; xr2=xv[2]; xr3=xv[3];
    } else {
      uint2 xv = *(const uint2*)(xfr + fi);
      xr0=bf2f((ushort_t)(xv.x&0xffffu)); xr1=bf2f((ushort_t)(xv.x>>16));
      xr2=bf2f((ushort_t)(xv.y&0xffffu)); xr3=bf2f((ushort_t)(xv.y>>16));
    }
    float o0 = acc[0]+ub[0]+xr0 + fmv[0]*__builtin_amdgcn_rcpf(1.f+__expf(-fmv[0]*fvv[0]));
    float o1 = acc[1]+ub[1]+xr1 + fmv[1]*__builtin_amdgcn_rcpf(1.f+__expf(-fmv[1]*fvv[1]));
    float o2 = acc[2]+ub[2]+xr2 + fmv[2]*__builtin_amdgcn_rcpf(1.f+__expf(-fmv[2]*fvv[2]));
    float o3 = acc[3]+ub[3]+xr3 + fmv[3]*__builtin_amdgcn_rcpf(1.f+__expf(-fmv[3]*fvv[3]));
    uint2 ov; ov.x=(unsigned)f2bf(o0)|((unsigned)f2bf(o1)<<16);
    ov.y=(unsigned)f2bf(o2)|((unsigned)f2bf(o3)<<16);
    *(uint2*)(ofr + fi) = ov;                                        // coalesced 8B
    // fused mean: reduce ROUNDED values over the 16 t-lanes
    float s0 = bf2f((ushort_t)(ov.x&0xffffu));
    float s1 = bf2f((ushort_t)(ov.x>>16));
    float s2m= bf2f((ushort_t)(ov.y&0xffffu));
    float s3 = bf2f((ushort_t)(ov.y>>16));
    #pragma unroll
    for (int mk=1; mk<16; mk<<=1){
      s0 += __shfl_xor(s0, mk);
      s1 += __shfl_xor(s1, mk);
      s2m+= __shfl_xor(s2m, mk);
      s3 += __shfl_xor(s3, mk);
    }
    if (t==0){
      f4v o = {s0*0.0625f, s1*0.0625f, s2m*0.0625f, s3*0.0625f};
      *(f4v*)(cmp + dq) = o;
    }
  }
}

// =====================================================================
// BOUNDARY UNIT (fp32 VALU; tiny)
// =====================================================================
__global__ __launch_bounds__(256)
void bnd1_kernel(const float* __restrict__ fb, const float* __restrict__ f_w,
                 const float* __restrict__ f_s, const float* __restrict__ kb,
                 const float* __restrict__ bWqT, const float* __restrict__ bbq,
                 float* __restrict__ fbq)
{
  int blk = blockIdx.x; int b = blk / LL, l = blk % LL;
  int d = threadIdx.x;
  __shared__ float fbrow[DD];
  __shared__ float qrow[DD];
  __shared__ float smx[32];
  fbrow[d] = fb[(size_t)(b*LL+l)*DD + d];
  __syncthreads();
  float q = bbq[d];
  for (int e=0;e<DD;e++) q += fbrow[e]*bWqT[(size_t)e*DD+d];
  qrow[d]=q;
  __syncthreads();
  if (d < NWW){
    float s=0.f; const float* kr = kb + (size_t)(b*NWW+d)*DD;
    for (int e=0;e<DD;e++) s += qrow[e]*kr[e];
    smx[d] = s*(1.0f/16.0f);
  }
  __syncthreads();
  if (d==0){
    float m2=-3.0e38f;
    for(int n=0;n<NWW;n++) m2=fmaxf(m2,smx[n]);
    float su=0.f;
    for(int n=0;n<NWW;n++){ float e=__expf(smx[n]-m2); smx[n]=e; su+=e; }
    float iv=1.f/su;
    for(int n=0;n<NWW;n++) smx[n]*=iv;
  }
  __syncthreads();
  float acc=0.f;
  for (int n=0;n<NWW;n++) acc += smx[n]*f_w[(size_t)(b*NWW+n)*DD+d];
  fbq[(size_t)(b*LL+l)*DD+d] = fbrow[d]*(acc + f_s[b*DD+d]);
}

__global__ __launch_bounds__(256)
void bnd2_kernel(const float* __restrict__ fbq, const float* __restrict__ fb,
                 const float* __restrict__ fm, const float* __restrict__ f_s,
                 float* __restrict__ bu_out)
{
  int blk = blockIdx.x; int b = blk/LL, l = blk%LL;
  int d = threadIdx.x;
  __shared__ float Sl[DD];
  __shared__ float aw[LL];
  Sl[d] = fbq[(size_t)(b*LL+l)*DD + d];
  __syncthreads();
  if (d < LL){
    float s=0.f; const float* fr = fbq + (size_t)(b*LL+d)*DD;
    const f4v* s4 = (const f4v*)Sl; const f4v* f4p = (const f4v*)fr;
    for (int e=0;e<DD/4;e++){
      f4v a=s4[e], c=f4p[e];
      s += a[0]*c[0]+a[1]*c[1]+a[2]*c[2]+a[3]*c[3];
    }
    aw[d] = s*(1.0f/16.0f);
  }
  __syncthreads();
  if (d==0){
    float m2=-3.0e38f;
    for(int n=0;n<LL;n++) m2=fmaxf(m2,aw[n]);
    float su=0.f;
    for(int n=0;n<LL;n++){ float e=__expf(aw[n]-m2); aw[n]=e; su+=e; }
    float iv=1.f/su;
    for(int n=0;n<LL;n++) aw[n]*=iv;
  }
  __syncthreads();
  float fsd = f_s[b*DD+d];
  const float* fmrow = fm + ((size_t)(b*LL+l)*LL)*DD + d;
  float acc=0.f;
  for (int m=0;m<LL;m++){
    float a  = aw[m];
    float fbv= fb[(size_t)(b*LL+m)*DD+d];
    float fmv= fmrow[(size_t)m*DD];
    float gm = 1.f/(1.f+__expf(-fmv*fsd));
    acc += a*(fbv + gm*fmv);
  }
  bu_out[(size_t)(b*LL+l)*DD+d] = acc + fb[(size_t)(b*LL+l)*DD+d];
}

// =====================================================================
// MOMENT UNIT — writes mu directly into d_out (fp32)
// =====================================================================
__global__ __launch_bounds__(256)
void moment_kernel(const float* __restrict__ cm, const float* __restrict__ bu,
                   const float* __restrict__ mu_in, float* __restrict__ mu_out,
                   const float* __restrict__ wbT, const float* __restrict__ wcT,
                   const float* __restrict__ mfbb, const float* __restrict__ mfcb)
{
  int blk = blockIdx.x;
  int oh = blk & 1; int bm = blk>>1; int b = bm/LL, m = bm%LL;
  int d = threadIdx.x;
  const int ob = oh*24;
  float accB[24], accC[24];
  #pragma unroll
  for (int o=0;o<24;o++){accB[o]=0.f;accC[o]=0.f;}
  for (int i=0;i<LL;i++){
    float bv = bu[(size_t)(b*LL+i)*DD+d];
    float cv = cm[((size_t)(b*LL+i)*LL+m)*DD+d];
    const float* wb = wbT + i*LL + ob;
    const float* wc = wcT + i*LL + ob;
    #pragma unroll
    for (int o=0;o<24;o+=4){
      f4v w1 = *(const f4v*)(wb+o);
      f4v w2 = *(const f4v*)(wc+o);
      accB[o  ]+=w1[0]*bv; accB[o+1]+=w1[1]*bv; accB[o+2]+=w1[2]*bv; accB[o+3]+=w1[3]*bv;
      accC[o  ]+=w2[0]*cv; accC[o+1]+=w2[1]*cv; accC[o+2]+=w2[2]*cv; accC[o+3]+=w2[3]*cv;
    }
  }
  float bum = bu[(size_t)(b*LL+m)*DD+d];
  #pragma unroll
  for (int o=0;o<24;o++){
    int oo = ob+o;
    size_t oi = ((size_t)(b*LL+oo)*LL+m)*DD + d;
    mu_out[oi] = accB[o]*bum + mfbb[oo] + accC[o] + mfcb[oo] + mu_in[oi];
  }
}

// =====================================================================
// PREP1
// =====================================================================
__global__ __launch_bounds__(256)
void prep1_kernel(const float* __restrict__ f_w, const float* __restrict__ f_s,
                  const float* __restrict__ bWq, const float* __restrict__ bWk,
                  const float* __restrict__ bbk,
                  const float* __restrict__ dcw_w, const float* __restrict__ dcw_b,
                  const float* __restrict__ dcs_w, const float* __restrict__ dcs_b,
                  const float* __restrict__ dcc_w, const float* __restrict__ cWq,
                  const float* __restrict__ ucc_w,
                  const float* __restrict__ mfb_w, const float* __restrict__ mfc_w,
                  float* __restrict__ kb, float* __restrict__ fwh,
                  float* __restrict__ fsh, float* __restrict__ bWqT,
                  ushort_t* __restrict__ dccf, ushort_t* __restrict__ cwqf,
                  ushort_t* __restrict__ uccf,
                  float* __restrict__ wbT, float* __restrict__ wcT)
{
  const int S0=20480, S1=5120, S2=256, S3=65536, S4=16384, S5=4096, S6=16384, S7=2304;
  const int TOT = S0+S1+S2+S3+S4+S5+S6+S7;
  int id = blockIdx.x*256 + threadIdx.x;
  int nth = gridDim.x*256;
  for (int x=id; x<TOT; x+=nth){
    int y=x;
    if (y < S0){
      int b=y/(NWW*DD); int r=y%(NWW*DD); int n=r/DD, dd2=r%DD;
      float s=bbk[dd2];
      const float* fr=f_w+(size_t)(b*NWW+n)*DD; const float* wr=bWk+(size_t)dd2*DD;
      for(int e=0;e<DD;e++) s+=fr[e]*wr[e];
      kb[y]=s; continue; }
    y-=S0;
    if (y < S1){
      int b=y/(NWW*DLL); int r=y%(NWW*DLL); int n=r/DLL, dl=r%DLL;
      float s=dcw_b[dl];
      const float* fr=f_w+(size_t)(b*NWW+n)*DD; const float* wr=dcw_w+(size_t)dl*DD;
      for(int e=0;e<DD;e++) s+=fr[e]*wr[e];
      fwh[y]=s; continue; }
    y-=S1;
    if (y < S2){
      int b=y/DLL, dl=y%DLL;
      float s=dcs_b[dl];
      const float* fr=f_s+(size_t)b*DD; const float* wr=dcs_w+(size_t)dl*DD;
      for(int e=0;e<DD;e++) s+=fr[e]*wr[e];
      fsh[y]=s; continue; }
    y-=S2;
    if (y < S3){ int e=y/DD, dd2=y%DD; bWqT[y] = bWq[(size_t)dd2*DD+e]; continue; }
    y-=S3;
    if (y < S4){
      int j=y&7, ln=(y>>3)&63, kk=(y>>9)&7, m0=y>>12;
      int mm=m0*16+(ln&15), k=kk*32+((ln>>4)<<3)+j;
      dccf[y]=f2bf(dcc_w[(size_t)mm*DD+k]); continue; }
    y-=S4;
    if (y < S5){
      int j=y&7, ln=(y>>3)&63, kk=(y>>9)&1, m0=y>>10;
      int mm=m0*16+(ln&15), k=kk*32+((ln>>4)<<3)+j;
      cwqf[y]=f2bf(cWq[(size_t)mm*DLL+k]); continue; }
    y-=S5;
    if (y < S6){
      int j=y&7, ln=(y>>3)&63, kk=(y>>9)&1, m0=y>>10;
      int mm=m0*16+(ln&15), k=kk*32+((ln>>4)<<3)+j;
      uccf[y]=f2bf(ucc_w[(size_t)mm*DLL+k]); continue; }
    y-=S6;
    { int i=y/LL, o=y%LL; wbT[y]=mfb_w[(size_t)o*LL+i]; wcT[y]=mfc_w[(size_t)o*LL+i]; }
  }
}

// =====================================================================
// PREP2
// =====================================================================
__global__ __launch_bounds__(256)
void prep2_kernel(const float* __restrict__ fwh, const float* __restrict__ cWk,
                  const float* __restrict__ cbk,
                  ushort_t* __restrict__ kcf, ushort_t* __restrict__ fwhtf)
{
  const int S0 = BB*2048, S1 = BB*2048;
  int id = blockIdx.x*256+threadIdx.x; int nth=gridDim.x*256;
  for (int x=id; x<S0+S1; x+=nth){
    int y=x;
    if (y < S0){
      int b=y>>11; int z=y&2047;
      int j=z&7, ln=(z>>3)&63, kk=(z>>9)&1, m0=z>>10;
      int n=m0*16+(ln&15), k=kk*32+((ln>>4)<<3)+j;
      float v=0.f;
      if (n<NWW){
        float s=cbk[k];
        const float* fr=fwh+(size_t)(b*NWW+n)*DLL; const float* wr=cWk+(size_t)k*DLL;
        for(int e=0;e<DLL;e++) s+=fr[e]*wr[e];
        v=s*0.125f;
      }
      kcf[y]=f2bf(v); continue; }
    y-=S0;
    {
      int b=y>>11; int z=y&2047;
      int j=z&7, ln=(z>>3)&63, m0=z>>9;
      int dl=m0*16+(ln&15), n=((ln>>4)<<3)+j;
      float v = (n<NWW)? fwh[(size_t)(b*NWW+n)*DLL+dl] : 0.f;
      fwhtf[y]=f2bf(v);
    }
  }
}

// =====================================================================
extern "C" void kernel_launch(void* const* d_in, const int* in_sizes, int n_in,
                              void* d_out, int out_size, void* d_ws, size_t ws_size,
                              hipStream_t stream)
{
  (void)in_sizes; (void)n_in; (void)out_size; (void)ws_size;
  const float* f_c  = (const float*)d_in[0];
  const float* f_m  = (const float*)d_in[1];
  const float* f_b  = (const float*)d_in[2];
  const float* f_w  = (const float*)d_in[3];
  const float* f_s  = (const float*)d_in[4];
  const float* bWq  = (const float*)d_in[5];
  const float* bbq  = (const float*)d_in[6];
  const float* bWk  = (const float*)d_in[7];
  const float* bbk  = (const float*)d_in[8];
  const float* cWq  = (const float*)d_in[9];
  const float* cbq  = (const float*)d_in[10];
  const float* cWk  = (const float*)d_in[11];
  const float* cbk  = (const float*)d_in[12];
  const float* dcc_w= (const float*)d_in[13];
  const float* dcc_b= (const float*)d_in[14];
  const float* dcw_w= (const float*)d_in[15];
  const float* dcw_b= (const float*)d_in[16];
  const float* dcs_w= (const float*)d_in[17];
  const float* dcs_b= (const float*)d_in[18];
  const float* ucc_w= (const float*)d_in[19];
  const float* ucc_b= (const float*)d_in[20];
  const float* mfb_w= (const float*)d_in[21];
  const float* mfb_b= (const float*)d_in[22];
  const float* mfc_w= (const float*)d_in[23];
  const float* mfc_b= (const float*)d_in[24];

  char* ws = (char*)d_ws;
  ushort_t* cu = (ushort_t*)(ws+OFF_CU);
  float* cmr  = (float*)(ws+OFF_CM);
  float* bu0  = (float*)(ws+OFF_BU0);
  float* bu1  = (float*)(ws+OFF_BU1);
  float* fbq  = (float*)(ws+OFF_FBQ);
  float* fwh  = (float*)(ws+OFF_FWH);
  float* fsh  = (float*)(ws+OFF_FSH);
  float* kb   = (float*)(ws+OFF_KB);
  float* bWqT = (float*)(ws+OFF_BWQT);
  float* wbT  = (float*)(ws+OFF_WBT);
  float* wcT  = (float*)(ws+OFF_WCT);
  ushort_t* dccf = (ushort_t*)(ws+OFF_DCCF);
  ushort_t* cwqf = (ushort_t*)(ws+OFF_CWQF);
  ushort_t* uccf = (ushort_t*)(ws+OFF_UCCF);
  ushort_t* kcf  = (ushort_t*)(ws+OFF_KCF);
  ushort_t* fwhtf= (ushort_t*)(ws+OFF_FWHTF);

  float* mu = (float*)d_out;
  float* out_bu = (float*)d_out + 2359296;

  prep1_kernel<<<128,256,0,stream>>>(f_w,f_s,bWq,bWk,bbk,dcw_w,dcw_b,dcs_w,dcs_b,
                                     dcc_w,cWq,ucc_w,mfb_w,mfc_w,
                                     kb,fwh,fsh,bWqT,dccf,cwqf,uccf,wbT,wcT);
  prep2_kernel<<<32,256,0,stream>>>(fwh,cWk,cbk,kcf,fwhtf);

  float* bu_cur = nullptr;
  for (int it=0; it<3; ++it){
    const float* fmsrc = (it==0)? f_m : mu;
    if (it==0)
      content_kernel<1><<<4608,128,0,stream>>>(f_c, cu, cmr, fmsrc, f_s, fsh, dcc_b, cbq, ucc_b,
                                               dccf,cwqf,uccf,kcf,fwhtf);
    else
      content_kernel<0><<<4608,128,0,stream>>>(cu, cu, cmr, fmsrc, f_s, fsh, dcc_b, cbq, ucc_b,
                                               dccf,cwqf,uccf,kcf,fwhtf);
    const float* fbsrc = (it==0)? f_b : bu_cur;
    float* bunew = (it==2)? out_bu : ((it==0)? bu0 : ((bu_cur==bu0)? bu1 : bu0));
    bnd1_kernel<<<192,256,0,stream>>>(fbsrc, f_w, f_s, kb, bWqT, bbq, fbq);
    bnd2_kernel<<<192,256,0,stream>>>(fbq, fbsrc, fmsrc, f_s, bunew);
    moment_kernel<<<384,256,0,stream>>>(cmr, bunew, fmsrc, mu, wbT, wcT, mfb_b, mfc_b);
    bu_cur = bunew;
  }
}

// Round 14
// 379.573 us; speedup vs baseline: 1.2572x; 1.0408x over previous
//
#include <hip/hip_runtime.h>

#define BB 4
#define LL 48
#define TT 16
#define NWW 20
#define DD 256
#define DLL 64

typedef __attribute__((ext_vector_type(8))) short s8v;
typedef __attribute__((ext_vector_type(4))) float f4v;
typedef unsigned short ushort_t;

#define FENCE() asm volatile("" ::: "memory")

// ---- ws layout (bytes) ----
#define OFF_CU     0ull           // bf16 cu state (FRAGMENT order): 75,497,472
#define OFF_CM     75497472ull
#define OFF_BU0    84934656ull
#define OFF_BU1    85131264ull
#define OFF_FBQ    85327872ull
#define OFF_FWH    85524480ull
#define OFF_FSH    85544960ull
#define OFF_KB     85545984ull
#define OFF_BWQT   85627904ull
#define OFF_WBT    85890048ull
#define OFF_WCT    85899264ull
#define OFF_DCCF   85908480ull
#define OFF_CWQF   85941248ull
#define OFF_UCCF   85949440ull
#define OFF_KCF    85982208ull
#define OFF_FWHTF  85998592ull

static __device__ __forceinline__ ushort_t f2bf(float f){
  unsigned u = __float_as_uint(f);
  return (ushort_t)((u + 0x7FFFu + ((u>>16)&1u)) >> 16);
}
static __device__ __forceinline__ float bf2f(ushort_t h){
  return __uint_as_float(((unsigned)h)<<16);
}
static __device__ __forceinline__ void st64(void* p, float a, float b, float c, float d){
  uint2 v; v.x = (unsigned)f2bf(a) | ((unsigned)f2bf(b)<<16);
  v.y = (unsigned)f2bf(c) | ((unsigned)f2bf(d)<<16);
  *(uint2*)p = v;
}

#define ADR64(row, cb) (((row)<<7) + ((cb) ^ (((row)&7)<<4)))
#define ADR32(row, cb) (((row)<<6) + ((cb) ^ (((row)&3)<<4)))

#define MFMA(a,b,c) __builtin_amdgcn_mfma_f32_16x16x32_bf16((a),(b),(c),0,0,0)

// =====================================================================
// CONTENT UNIT (R11 structure): 4 independent waves per block, one
// (b,l,m) tile per wave, private 8 KB LDS slice, no hardware barriers.
// Next-phase A-fragment loads hoisted before each fence.
// cu in FRAGMENT ORDER: element (t, d=kk*32+gg*8+j) at ushort offset
// tile*4096 + kk*512 + gg*128 + t*8 + j.
// NEW (R14): FIRST=0 residual is reconstructed from the xb registers
// via cross-lane __shfl (no global re-read of cu: -75.5 MB fetch).
//   lane (t,g), m0 needs d=(m0>>1)*32+gg'*8+(g&1)*4+r, gg'=(m0&1)*2+(g>>1)
//   -> source lane t+16*gg', words of xb[m0>>1]: (g&1)? (z,w):(x,y).
// LDS overlay per tile:
//   0..2048 : HLDS -> AWLDS(0-1024) -> CQLO -> ACLDS(0-1024)
//   2048..4096 : QLDS -> CQHI -> CCHLDS
//   4096..8192 : HT [64][32] (zero-padded cols 16..31)
// Epilogue stages rounded bf16 outputs into 0..8192 for the fused T-mean.
// =====================================================================
template<int FIRST>
__global__ __launch_bounds__(256)
void content_kernel(const void* cusrc_, ushort_t* cudst, float* __restrict__ cm,
                    const float* __restrict__ fm_src, const float* __restrict__ fsg,
                    const float* __restrict__ fsh, const float* __restrict__ dccb,
                    const float* __restrict__ cbq, const float* __restrict__ uccb,
                    const ushort_t* __restrict__ dccf, const ushort_t* __restrict__ cwqf,
                    const ushort_t* __restrict__ uccf, const ushort_t* __restrict__ kcf,
                    const ushort_t* __restrict__ fwhtf)
{
  __shared__ __align__(16) char sm_all[4][8192];
  const int wid = threadIdx.x >> 6;
  const int lane = threadIdx.x & 63;
  char* sm = sm_all[wid];
  const int t = lane & 15, g = lane >> 4;
  const int tile = blockIdx.x*4 + wid;
  const int b = tile / (LL*LL);

  { // zero HT pad cols (s=16..31)
    f4v z = {0.f,0.f,0.f,0.f};
    *(f4v*)(sm + 4096 + ADR32(lane, 32)) = z;
    *(f4v*)(sm + 4096 + ADR32(lane, 48)) = z;
  }

  // ---- X B-fragments: X[t][k], k = kk*32+g*8+j ----
  s8v xb[8];
  if (FIRST){
    const float* xp = (const float*)cusrc_ + (size_t)tile*4096 + t*DD + g*8;
    #pragma unroll
    for (int kk=0;kk<8;kk++){
      f4v lo = *(const f4v*)(xp + kk*32);
      f4v hi = *(const f4v*)(xp + kk*32 + 4);
      s8v v;
      v[0]=(short)f2bf(lo[0]); v[1]=(short)f2bf(lo[1]);
      v[2]=(short)f2bf(lo[2]); v[3]=(short)f2bf(lo[3]);
      v[4]=(short)f2bf(hi[0]); v[5]=(short)f2bf(hi[1]);
      v[6]=(short)f2bf(hi[2]); v[7]=(short)f2bf(hi[3]);
      xb[kk]=v;
    }
  } else {
    // fragment-order cu: fully coalesced (lane*16B within each kk-chunk)
    const ushort_t* xp = (const ushort_t*)cusrc_ + (size_t)tile*4096 + lane*8;
    #pragma unroll
    for (int kk=0;kk<8;kk++) xb[kk] = *(const s8v*)(xp + kk*512);
  }

  // ---- H^T = dcc_w @ X^T + dcc_b ----
  f4v accH[4];
  {
    f4v z = {0.f,0.f,0.f,0.f};
    accH[0]=z; accH[1]=z; accH[2]=z; accH[3]=z;
  }
  #pragma unroll
  for (int kk=0;kk<8;kk++){
    #pragma unroll
    for (int m0=0;m0<4;m0++){
      s8v a = *(const s8v*)(dccf + (((m0<<3)+kk)<<9) + (lane<<3));
      accH[m0] = MFMA(a, xb[kk], accH[m0]);
    }
  }
  // hoisted A-fragments for the Q phase
  s8v cwa[8];
  #pragma unroll
  for (int i=0;i<8;i++) cwa[i] = *(const s8v*)(cwqf + (i<<9) + (lane<<3));
  #pragma unroll
  for (int m0=0;m0<4;m0++){
    f4v acc = accH[m0];
    f4v bi = *(const f4v*)(dccb + m0*16 + g*4);
    acc[0]+=bi[0]; acc[1]+=bi[1]; acc[2]+=bi[2]; acc[3]+=bi[3];
    accH[m0]=acc;
    st64(sm + ADR64(t, m0*32 + g*8), acc[0],acc[1],acc[2],acc[3]);   // HLDS [t][dl]
    #pragma unroll
    for (int r=0;r<4;r++)                                            // HT [dl][t]
      *(ushort_t*)(sm + 4096 + ADR32(m0*16 + g*4 + r, t*2)) = f2bf(acc[r]);
  }
  FENCE();  // A

  // ---- q^T = cWq @ H^T + cbq ----
  s8v hb0 = *(const s8v*)(sm + ADR64(t, g*16));
  s8v hb1 = *(const s8v*)(sm + ADR64(t, 64 + g*16));
  #pragma unroll
  for (int m0=0;m0<4;m0++){
    f4v acc = {0.f,0.f,0.f,0.f};
    acc = MFMA(cwa[m0*2  ], hb0, acc);
    acc = MFMA(cwa[m0*2+1], hb1, acc);
    f4v bi = *(const f4v*)(cbq + m0*16 + g*4);
    st64(sm + 2048 + ADR64(t, m0*32 + g*8),
         acc[0]+bi[0], acc[1]+bi[1], acc[2]+bi[2], acc[3]+bi[3]);    // QLDS
  }
  // hoisted A-fragments for the s phase
  s8v kca[4];
  #pragma unroll
  for (int i=0;i<4;i++) kca[i] = *(const s8v*)(kcf + (b<<11) + (i<<9) + (lane<<3));
  FENCE();  // B

  // ---- s^T = (kc/8) @ q^T ----
  s8v qb0 = *(const s8v*)(sm + 2048 + ADR64(t, g*16));
  s8v qb1 = *(const s8v*)(sm + 2048 + ADR64(t, 64 + g*16));
  f4v sA[2];
  #pragma unroll
  for (int m0=0;m0<2;m0++){
    f4v acc = {0.f,0.f,0.f,0.f};
    acc = MFMA(kca[m0*2  ], qb0, acc);
    acc = MFMA(kca[m0*2+1], qb1, acc);
    sA[m0]=acc;
  }
  // softmax over n
  float mx = -3.0e38f;
  #pragma unroll
  for (int m0=0;m0<2;m0++){
    #pragma unroll
    for (int r=0;r<4;r++){
      int n = m0*16 + g*4 + r;
      if (n < NWW) mx = fmaxf(mx, sA[m0][r]);
    }
  }
  mx = fmaxf(mx, __shfl_xor(mx, 16));
  mx = fmaxf(mx, __shfl_xor(mx, 32));
  float ex[8]; float sum = 0.f;
  #pragma unroll
  for (int m0=0;m0<2;m0++){
    #pragma unroll
    for (int r=0;r<4;r++){
      int n = m0*16 + g*4 + r;
      float e = (n < NWW) ? __expf(sA[m0][r]-mx) : 0.f;
      ex[m0*4+r]=e; sum+=e;
    }
  }
  sum += __shfl_xor(sum,16);
  sum += __shfl_xor(sum,32);
  float inv = 1.f/sum;
  #pragma unroll
  for (int m0=0;m0<2;m0++)
    st64(sm + ADR32(t, m0*32 + g*8),
         ex[m0*4]*inv, ex[m0*4+1]*inv, ex[m0*4+2]*inv, ex[m0*4+3]*inv); // AWLDS @0
  // hoisted A-fragments for the fcaq phase
  s8v fwa[4];
  #pragma unroll
  for (int i=0;i<4;i++) fwa[i] = *(const s8v*)(fwhtf + (b<<11) + (i<<9) + (lane<<3));
  FENCE();  // C

  // ---- f_caq^T = fwh^T @ aw^T ; f_cq (x 8^-0.5, hi/lo split) ----
  s8v awb = *(const s8v*)(sm + ADR32(t, g*16));
  FENCE();  // C2
  #pragma unroll
  for (int m0=0;m0<4;m0++){
    f4v z = {0.f,0.f,0.f,0.f};
    f4v acc = MFMA(fwa[m0], awb, z);
    f4v fv = *(const f4v*)(fsh + b*DLL + m0*16 + g*4);
    float cq0 = accH[m0][0]*(acc[0]+fv[0])*0.35355339059f;
    float cq1 = accH[m0][1]*(acc[1]+fv[1])*0.35355339059f;
    float cq2 = accH[m0][2]*(acc[2]+fv[2])*0.35355339059f;
    float cq3 = accH[m0][3]*(acc[3]+fv[3])*0.35355339059f;
    ushort_t h0=f2bf(cq0),h1=f2bf(cq1),h2=f2bf(cq2),h3=f2bf(cq3);
    uint2 hv; hv.x=(unsigned)h0|((unsigned)h1<<16); hv.y=(unsigned)h2|((unsigned)h3<<16);
    *(uint2*)(sm + 2048 + ADR64(t, m0*32+g*8)) = hv;                 // CQHI @2048
    uint2 lv;
    lv.x = (unsigned)f2bf(cq0-bf2f(h0)) | ((unsigned)f2bf(cq1-bf2f(h1))<<16);
    lv.y = (unsigned)f2bf(cq2-bf2f(h2)) | ((unsigned)f2bf(cq3-bf2f(h3))<<16);
    *(uint2*)(sm + ADR64(t, m0*32+g*8)) = lv;                        // CQLO @0
  }
  FENCE();  // D

  // ---- S2 = f_cq f_cq^T (hh+hl+lh; symmetric) ----
  s8v ch0 = *(const s8v*)(sm + 2048 + ADR64(t, g*16));
  s8v ch1 = *(const s8v*)(sm + 2048 + ADR64(t, 64+g*16));
  s8v cl0 = *(const s8v*)(sm + ADR64(t, g*16));
  s8v cl1 = *(const s8v*)(sm + ADR64(t, 64+g*16));
  f4v s2 = {0.f,0.f,0.f,0.f};
  s2 = MFMA(ch0, ch0, s2); s2 = MFMA(ch1, ch1, s2);
  s2 = MFMA(ch0, cl0, s2); s2 = MFMA(ch1, cl1, s2);
  s2 = MFMA(cl0, ch0, s2); s2 = MFMA(cl1, ch1, s2);
  float mx2 = fmaxf(fmaxf(s2[0],s2[1]), fmaxf(s2[2],s2[3]));
  mx2 = fmaxf(mx2, __shfl_xor(mx2,16));
  mx2 = fmaxf(mx2, __shfl_xor(mx2,32));
  float e0=__expf(s2[0]-mx2), e1=__expf(s2[1]-mx2), e2=__expf(s2[2]-mx2), e3=__expf(s2[3]-mx2);
  float su = e0+e1+e2+e3;
  su += __shfl_xor(su,16);
  su += __shfl_xor(su,32);
  float inv2 = 1.f/su;
  FENCE();  // D2
  st64(sm + ADR32(t, g*8), e0*inv2, e1*inv2, e2*inv2, e3*inv2);      // ACLDS @0
  { uint2 zz; zz.x=0u; zz.y=0u; *(uint2*)(sm + ADR32(t, 32+g*8)) = zz; }
  FENCE();  // E

  // ---- f_cc_hat^T = H^T @ A_c^T  (A from HT, B from ACLDS) ----
  s8v acb = *(const s8v*)(sm + ADR32(t, g*16));
  #pragma unroll
  for (int m0=0;m0<4;m0++){
    s8v a = *(const s8v*)(sm + 4096 + ADR32(m0*16 + t, g*16));
    f4v z = {0.f,0.f,0.f,0.f};
    f4v acc = MFMA(a, acb, z);
    st64(sm + 2048 + ADR64(t, m0*32+g*8), acc[0],acc[1],acc[2],acc[3]); // CCHLDS
  }
  FENCE();  // F

  // ---- f_cc^T = ucc_w @ f_cc_hat^T ; out = f_cc + fc + sigmoid(fm*fs)*fm ----
  s8v cc0 = *(const s8v*)(sm + 2048 + ADR64(t, g*16));
  s8v cc1 = *(const s8v*)(sm + 2048 + ADR64(t, 64+g*16));
  FENCE();  // F2
  const float* fmp = fm_src + (size_t)tile*DD;
  const float* fsp = fsg + b*DD;
  const int frofs = t*8 + (g>>1)*128 + (g&1)*4;
  ushort_t* ofr = cudst + (size_t)tile*4096 + frofs;
  const float* xf = (const float*)cusrc_ + (size_t)tile*4096 + t*DD;  // FIRST=1 path
  #pragma unroll
  for (int m0=0;m0<16;m0++){
    f4v acc = {0.f,0.f,0.f,0.f};
    s8v a0 = *(const s8v*)(uccf + (((m0<<1)  )<<9) + (lane<<3));
    s8v a1 = *(const s8v*)(uccf + (((m0<<1)+1)<<9) + (lane<<3));
    acc = MFMA(a0, cc0, acc);
    acc = MFMA(a1, cc1, acc);
    const int dq = m0*16 + g*4;
    const int fi = (m0>>1)*512 + (m0&1)*256;
    f4v ub  = *(const f4v*)(uccb + dq);
    f4v fmv = *(const f4v*)(fmp + dq);
    f4v fvv = *(const f4v*)(fsp + dq);
    float xr0,xr1,xr2,xr3;
    if (FIRST){
      f4v xv = *(const f4v*)(xf + dq);
      xr0=xv[0]; xr1=xv[1]; xr2=xv[2]; xr3=xv[3];
    } else {
      // residual from xb registers via cross-lane shuffle (no global read)
      uint4 xw = __builtin_bit_cast(uint4, xb[m0>>1]);
      const int srcl = t + (((m0&1)*2 + (g>>1)) << 4);
      unsigned w0 = (unsigned)__shfl((int)xw.x, srcl);
      unsigned w1 = (unsigned)__shfl((int)xw.y, srcl);
      unsigned w2 = (unsigned)__shfl((int)xw.z, srcl);
      unsigned w3 = (unsigned)__shfl((int)xw.w, srcl);
      unsigned rx = (g&1) ? w2 : w0;
      unsigned ry = (g&1) ? w3 : w1;
      xr0=bf2f((ushort_t)(rx&0xffffu)); xr1=bf2f((ushort_t)(rx>>16));
      xr2=bf2f((ushort_t)(ry&0xffffu)); xr3=bf2f((ushort_t)(ry>>16));
    }
    float o0 = acc[0]+ub[0]+xr0 + fmv[0]*__builtin_amdgcn_rcpf(1.f+__expf(-fmv[0]*fvv[0]));
    float o1 = acc[1]+ub[1]+xr1 + fmv[1]*__builtin_amdgcn_rcpf(1.f+__expf(-fmv[1]*fvv[1]));
    float o2 = acc[2]+ub[2]+xr2 + fmv[2]*__builtin_amdgcn_rcpf(1.f+__expf(-fmv[2]*fvv[2]));
    float o3 = acc[3]+ub[3]+xr3 + fmv[3]*__builtin_amdgcn_rcpf(1.f+__expf(-fmv[3]*fvv[3]));
    uint2 ov; ov.x=(unsigned)f2bf(o0)|((unsigned)f2bf(o1)<<16);
    ov.y=(unsigned)f2bf(o2)|((unsigned)f2bf(o3)<<16);
    *(uint2*)(ofr + fi) = ov;                                        // coalesced 8B
    // stage rounded bf16 row into LDS for the fused T-mean
    *(uint2*)(sm + (t<<9) + ((dq*2) ^ ((t&15)<<3))) = ov;
  }
  FENCE();  // G

  // ---- fused meank: cm[tile][d] = mean over t of rounded outputs ----
  {
    const int d0 = lane*4;
    float s0=0.f,s1=0.f,s2=0.f,s3=0.f;
    #pragma unroll
    for (int tt=0;tt<TT;tt++){
      uint2 v = *(const uint2*)(sm + (tt<<9) + ((d0*2) ^ ((tt&15)<<3)));
      s0 += bf2f((ushort_t)(v.x&0xffffu)); s1 += bf2f((ushort_t)(v.x>>16));
      s2 += bf2f((ushort_t)(v.y&0xffffu)); s3 += bf2f((ushort_t)(v.y>>16));
    }
    f4v o = {s0*0.0625f, s1*0.0625f, s2*0.0625f, s3*0.0625f};
    *(f4v*)(cm + (size_t)tile*DD + d0) = o;
  }
}

// =====================================================================
// BOUNDARY UNIT (fp32 VALU; tiny)
// =====================================================================
__global__ __launch_bounds__(256)
void bnd1_kernel(const float* __restrict__ fb, const float* __restrict__ f_w,
                 const float* __restrict__ f_s, const float* __restrict__ kb,
                 const float* __restrict__ bWqT, const float* __restrict__ bbq,
                 float* __restrict__ fbq)
{
  int blk = blockIdx.x; int b = blk / LL, l = blk % LL;
  int d = threadIdx.x;
  __shared__ float fbrow[DD];
  __shared__ float qrow[DD];
  __shared__ float smx[32];
  fbrow[d] = fb[(size_t)(b*LL+l)*DD + d];
  __syncthreads();
  float q = bbq[d];
  for (int e=0;e<DD;e++) q += fbrow[e]*bWqT[(size_t)e*DD+d];
  qrow[d]=q;
  __syncthreads();
  if (d < NWW){
    float s=0.f; const float* kr = kb + (size_t)(b*NWW+d)*DD;
    for (int e=0;e<DD;e++) s += qrow[e]*kr[e];
    smx[d] = s*(1.0f/16.0f);
  }
  __syncthreads();
  if (d==0){
    float m2=-3.0e38f;
    for(int n=0;n<NWW;n++) m2=fmaxf(m2,smx[n]);
    float su=0.f;
    for(int n=0;n<NWW;n++){ float e=__expf(smx[n]-m2); smx[n]=e; su+=e; }
    float iv=1.f/su;
    for(int n=0;n<NWW;n++) smx[n]*=iv;
  }
  __syncthreads();
  float acc=0.f;
  for (int n=0;n<NWW;n++) acc += smx[n]*f_w[(size_t)(b*NWW+n)*DD+d];
  fbq[(size_t)(b*LL+l)*DD+d] = fbrow[d]*(acc + f_s[b*DD+d]);
}

__global__ __launch_bounds__(256)
void bnd2_kernel(const float* __restrict__ fbq, const float* __restrict__ fb,
                 const float* __restrict__ fm, const float* __restrict__ f_s,
                 float* __restrict__ bu_out)
{
  int blk = blockIdx.x; int b = blk/LL, l = blk%LL;
  int d = threadIdx.x;
  __shared__ float Sl[DD];
  __shared__ float aw[LL];
  Sl[d] = fbq[(size_t)(b*LL+l)*DD + d];
  __syncthreads();
  if (d < LL){
    float s=0.f; const float* fr = fbq + (size_t)(b*LL+d)*DD;
    const f4v* s4 = (const f4v*)Sl; const f4v* f4p = (const f4v*)fr;
    for (int e=0;e<DD/4;e++){
      f4v a=s4[e], c=f4p[e];
      s += a[0]*c[0]+a[1]*c[1]+a[2]*c[2]+a[3]*c[3];
    }
    aw[d] = s*(1.0f/16.0f);
  }
  __syncthreads();
  if (d==0){
    float m2=-3.0e38f;
    for(int n=0;n<LL;n++) m2=fmaxf(m2,aw[n]);
    float su=0.f;
    for(int n=0;n<LL;n++){ float e=__expf(aw[n]-m2); aw[n]=e; su+=e; }
    float iv=1.f/su;
    for(int n=0;n<LL;n++) aw[n]*=iv;
  }
  __syncthreads();
  float fsd = f_s[b*DD+d];
  const float* fmrow = fm + ((size_t)(b*LL+l)*LL)*DD + d;
  float acc=0.f;
  for (int m=0;m<LL;m++){
    float a  = aw[m];
    float fbv= fb[(size_t)(b*LL+m)*DD+d];
    float fmv= fmrow[(size_t)m*DD];
    float gm = 1.f/(1.f+__expf(-fmv*fsd));
    acc += a*(fbv + gm*fmv);
  }
  bu_out[(size_t)(b*LL+l)*DD+d] = acc + fb[(size_t)(b*LL+l)*DD+d];
}

// =====================================================================
// MOMENT UNIT — writes mu directly into d_out (fp32)
// =====================================================================
__global__ __launch_bounds__(256)
void moment_kernel(const float* __restrict__ cm, const float* __restrict__ bu,
                   const float* __restrict__ mu_in, float* __restrict__ mu_out,
                   const float* __restrict__ wbT, const float* __restrict__ wcT,
                   const float* __restrict__ mfbb, const float* __restrict__ mfcb)
{
  int blk = blockIdx.x;
  int oh = blk & 1; int bm = blk>>1; int b = bm/LL, m = bm%LL;
  int d = threadIdx.x;
  const int ob = oh*24;
  float accB[24], accC[24];
  #pragma unroll
  for (int o=0;o<24;o++){accB[o]=0.f;accC[o]=0.f;}
  for (int i=0;i<LL;i++){
    float bv = bu[(size_t)(b*LL+i)*DD+d];
    float cv = cm[((size_t)(b*LL+i)*LL+m)*DD+d];
    const float* wb = wbT + i*LL + ob;
    const float* wc = wcT + i*LL + ob;
    #pragma unroll
    for (int o=0;o<24;o+=4){
      f4v w1 = *(const f4v*)(wb+o);
      f4v w2 = *(const f4v*)(wc+o);
      accB[o  ]+=w1[0]*bv; accB[o+1]+=w1[1]*bv; accB[o+2]+=w1[2]*bv; accB[o+3]+=w1[3]*bv;
      accC[o  ]+=w2[0]*cv; accC[o+1]+=w2[1]*cv; accC[o+2]+=w2[2]*cv; accC[o+3]+=w2[3]*cv;
    }
  }
  float bum = bu[(size_t)(b*LL+m)*DD+d];
  #pragma unroll
  for (int o=0;o<24;o++){
    int oo = ob+o;
    size_t oi = ((size_t)(b*LL+oo)*LL+m)*DD + d;
    mu_out[oi] = accB[o]*bum + mfbb[oo] + accC[o] + mfcb[oo] + mu_in[oi];
  }
}

// =====================================================================
// PREP1
// =====================================================================
__global__ __launch_bounds__(256)
void prep1_kernel(const float* __restrict__ f_w, const float* __restrict__ f_s,
                  const float* __restrict__ bWq, const float* __restrict__ bWk,
                  const float* __restrict__ bbk,
                  const float* __restrict__ dcw_w, const float* __restrict__ dcw_b,
                  const float* __restrict__ dcs_w, const float* __restrict__ dcs_b,
                  const float* __restrict__ dcc_w, const float* __restrict__ cWq,
                  const float* __restrict__ ucc_w,
                  const float* __restrict__ mfb_w, const float* __restrict__ mfc_w,
                  float* __restrict__ kb, float* __restrict__ fwh,
                  float* __restrict__ fsh, float* __restrict__ bWqT,
                  ushort_t* __restrict__ dccf, ushort_t* __restrict__ cwqf,
                  ushort_t* __restrict__ uccf,
                  float* __restrict__ wbT, float* __restrict__ wcT)
{
  const int S0=20480, S1=5120, S2=256, S3=65536, S4=16384, S5=4096, S6=16384, S7=2304;
  const int TOT = S0+S1+S2+S3+S4+S5+S6+S7;
  int id = blockIdx.x*256 + threadIdx.x;
  int nth = gridDim.x*256;
  for (int x=id; x<TOT; x+=nth){
    int y=x;
    if (y < S0){
      int b=y/(NWW*DD); int r=y%(NWW*DD); int n=r/DD, dd2=r%DD;
      float s=bbk[dd2];
      const float* fr=f_w+(size_t)(b*NWW+n)*DD; const float* wr=bWk+(size_t)dd2*DD;
      for(int e=0;e<DD;e++) s+=fr[e]*wr[e];
      kb[y]=s; continue; }
    y-=S0;
    if (y < S1){
      int b=y/(NWW*DLL); int r=y%(NWW*DLL); int n=r/DLL, dl=r%DLL;
      float s=dcw_b[dl];
      const float* fr=f_w+(size_t)(b*NWW+n)*DD; const float* wr=dcw_w+(size_t)dl*DD;
      for(int e=0;e<DD;e++) s+=fr[e]*wr[e];
      fwh[y]=s; continue; }
    y-=S1;
    if (y < S2){
      int b=y/DLL, dl=y%DLL;
      float s=dcs_b[dl];
      const float* fr=f_s+(size_t)b*DD; const float* wr=dcs_w+(size_t)dl*DD;
      for(int e=0;e<DD;e++) s+=fr[e]*wr[e];
      fsh[y]=s; continue; }
    y-=S2;
    if (y < S3){ int e=y/DD, dd2=y%DD; bWqT[y] = bWq[(size_t)dd2*DD+e]; continue; }
    y-=S3;
    if (y < S4){
      int j=y&7, ln=(y>>3)&63, kk=(y>>9)&7, m0=y>>12;
      int mm=m0*16+(ln&15), k=kk*32+((ln>>4)<<3)+j;
      dccf[y]=f2bf(dcc_w[(size_t)mm*DD+k]); continue; }
    y-=S4;
    if (y < S5){
      int j=y&7, ln=(y>>3)&63, kk=(y>>9)&1, m0=y>>10;
      int mm=m0*16+(ln&15), k=kk*32+((ln>>4)<<3)+j;
      cwqf[y]=f2bf(cWq[(size_t)mm*DLL+k]); continue; }
    y-=S5;
    if (y < S6){
      int j=y&7, ln=(y>>3)&63, kk=(y>>9)&1, m0=y>>10;
      int mm=m0*16+(ln&15), k=kk*32+((ln>>4)<<3)+j;
      uccf[y]=f2bf(ucc_w[(size_t)mm*DLL+k]); continue; }
    y-=S6;
    { int i=y/LL, o=y%LL; wbT[y]=mfb_w[(size_t)o*LL+i]; wcT[y]=mfc_w[(size_t)o*LL+i]; }
  }
}

// =====================================================================
// PREP2
// =====================================================================
__global__ __launch_bounds__(256)
void prep2_kernel(const float* __restrict__ fwh, const float* __restrict__ cWk,
                  const float* __restrict__ cbk,
                  ushort_t* __restrict__ kcf, ushort_t* __restrict__ fwhtf)
{
  const int S0 = BB*2048, S1 = BB*2048;
  int id = blockIdx.x*256+threadIdx.x; int nth=gridDim.x*256;
  for (int x=id; x<S0+S1; x+=nth){
    int y=x;
    if (y < S0){
      int b=y>>11; int z=y&2047;
      int j=z&7, ln=(z>>3)&63, kk=(z>>9)&1, m0=z>>10;
      int n=m0*16+(ln&15), k=kk*32+((ln>>4)<<3)+j;
      float v=0.f;
      if (n<NWW){
        float s=cbk[k];
        const float* fr=fwh+(size_t)(b*NWW+n)*DLL; const float* wr=cWk+(size_t)k*DLL;
        for(int e=0;e<DLL;e++) s+=fr[e]*wr[e];
        v=s*0.125f;
      }
      kcf[y]=f2bf(v); continue; }
    y-=S0;
    {
      int b=y>>11; int z=y&2047;
      int j=z&7, ln=(z>>3)&63, m0=z>>9;
      int dl=m0*16+(ln&15), n=((ln>>4)<<3)+j;
      float v = (n<NWW)? fwh[(size_t)(b*NWW+n)*DLL+dl] : 0.f;
      fwhtf[y]=f2bf(v);
    }
  }
}

// =====================================================================
extern "C" void kernel_launch(void* const* d_in, const int* in_sizes, int n_in,
                              void* d_out, int out_size, void* d_ws, size_t ws_size,
                              hipStream_t stream)
{
  (void)in_sizes; (void)n_in; (void)out_size; (void)ws_size;
  const float* f_c  = (const float*)d_in[0];
  const float* f_m  = (const float*)d_in[1];
  const float* f_b  = (const float*)d_in[2];
  const float* f_w  = (const float*)d_in[3];
  const float* f_s  = (const float*)d_in[4];
  const float* bWq  = (const float*)d_in[5];
  const float* bbq  = (const float*)d_in[6];
  const float* bWk  = (const float*)d_in[7];
  const float* bbk  = (const float*)d_in[8];
  const float* cWq  = (const float*)d_in[9];
  const float* cbq  = (const float*)d_in[10];
  const float* cWk  = (const float*)d_in[11];
  const float* cbk  = (const float*)d_in[12];
  const float* dcc_w= (const float*)d_in[13];
  const float* dcc_b= (const float*)d_in[14];
  const float* dcw_w= (const float*)d_in[15];
  const float* dcw_b= (const float*)d_in[16];
  const float* dcs_w= (const float*)d_in[17];
  const float* dcs_b= (const float*)d_in[18];
  const float* ucc_w= (const float*)d_in[19];
  const float* ucc_b= (const float*)d_in[20];
  const float* mfb_w= (const float*)d_in[21];
  const float* mfb_b= (const float*)d_in[22];
  const float* mfc_w= (const float*)d_in[23];
  const float* mfc_b= (const float*)d_in[24];

  char* ws = (char*)d_ws;
  ushort_t* cu = (ushort_t*)(ws+OFF_CU);
  float* cmr  = (float*)(ws+OFF_CM);
  float* bu0  = (float*)(ws+OFF_BU0);
  float* bu1  = (float*)(ws+OFF_BU1);
  float* fbq  = (float*)(ws+OFF_FBQ);
  float* fwh  = (float*)(ws+OFF_FWH);
  float* fsh  = (float*)(ws+OFF_FSH);
  float* kb   = (float*)(ws+OFF_KB);
  float* bWqT = (float*)(ws+OFF_BWQT);
  float* wbT  = (float*)(ws+OFF_WBT);
  float* wcT  = (float*)(ws+OFF_WCT);
  ushort_t* dccf = (ushort_t*)(ws+OFF_DCCF);
  ushort_t* cwqf = (ushort_t*)(ws+OFF_CWQF);
  ushort_t* uccf = (ushort_t*)(ws+OFF_UCCF);
  ushort_t* kcf  = (ushort_t*)(ws+OFF_KCF);
  ushort_t* fwhtf= (ushort_t*)(ws+OFF_FWHTF);

  float* mu = (float*)d_out;
  float* out_bu = (float*)d_out + 2359296;

  prep1_kernel<<<128,256,0,stream>>>(f_w,f_s,bWq,bWk,bbk,dcw_w,dcw_b,dcs_w,dcs_b,
                                     dcc_w,cWq,ucc_w,mfb_w,mfc_w,
                                     kb,fwh,fsh,bWqT,dccf,cwqf,uccf,wbT,wcT);
  prep2_kernel<<<32,256,0,stream>>>(fwh,cWk,cbk,kcf,fwhtf);

  float* bu_cur = nullptr;
  for (int it=0; it<3; ++it){
    const float* fmsrc = (it==0)? f_m : mu;
    if (it==0)
      content_kernel<1><<<2304,256,0,stream>>>(f_c, cu, cmr, fmsrc, f_s, fsh, dcc_b, cbq, ucc_b,
                                               dccf,cwqf,uccf,kcf,fwhtf);
    else
      content_kernel<0><<<2304,256,0,stream>>>(cu, cu, cmr, fmsrc, f_s, fsh, dcc_b, cbq, ucc_b,
                                               dccf,cwqf,uccf,kcf,fwhtf);
    const float* fbsrc = (it==0)? f_b : bu_cur;
    float* bunew = (it==2)? out_bu : ((it==0)? bu0 : ((bu_cur==bu0)? bu1 : bu0));
    bnd1_kernel<<<192,256,0,stream>>>(fbsrc, f_w, f_s, kb, bWqT, bbq, fbq);
    bnd2_kernel<<<192,256,0,stream>>>(fbq, fbsrc, fmsrc, f_s, bunew);
    moment_kernel<<<384,256,0,stream>>>(cmr, bunew, fmsrc, mu, wbT, wcT, mfb_b, mfc_b);
    bu_cur = bunew;
  }
}

// Round 15
// 371.467 us; speedup vs baseline: 1.2846x; 1.0218x over previous
//
#include <hip/hip_runtime.h>

#define BB 4
#define LL 48
#define TT 16
#define NWW 20
#define DD 256
#define DLL 64

typedef __attribute__((ext_vector_type(8))) short s8v;
typedef __attribute__((ext_vector_type(4))) float f4v;
typedef unsigned short ushort_t;

#define FENCE() asm volatile("" ::: "memory")

// ---- ws layout (bytes) ----
#define OFF_CU     0ull           // bf16 cu state (FRAGMENT order): 75,497,472
#define OFF_CM     75497472ull
#define OFF_BU0    84934656ull
#define OFF_BU1    85131264ull
#define OFF_FBQ    85327872ull
#define OFF_FWH    85524480ull
#define OFF_FSH    85544960ull
#define OFF_KB     85545984ull
#define OFF_BWQT   85627904ull
#define OFF_WBT    85890048ull
#define OFF_WCT    85899264ull
#define OFF_DCCF   85908480ull
#define OFF_CWQF   85941248ull
#define OFF_UCCF   85949440ull
#define OFF_KCF    85982208ull
#define OFF_FWHTF  85998592ull

static __device__ __forceinline__ ushort_t f2bf(float f){
  unsigned u = __float_as_uint(f);
  return (ushort_t)((u + 0x7FFFu + ((u>>16)&1u)) >> 16);
}
static __device__ __forceinline__ float bf2f(ushort_t h){
  return __uint_as_float(((unsigned)h)<<16);
}
static __device__ __forceinline__ void st64(void* p, float a, float b, float c, float d){
  uint2 v; v.x = (unsigned)f2bf(a) | ((unsigned)f2bf(b)<<16);
  v.y = (unsigned)f2bf(c) | ((unsigned)f2bf(d)<<16);
  *(uint2*)p = v;
}

#define ADR64(row, cb) (((row)<<7) + ((cb) ^ (((row)&7)<<4)))
#define ADR32(row, cb) (((row)<<6) + ((cb) ^ (((row)&3)<<4)))

#define MFMA(a,b,c) __builtin_amdgcn_mfma_f32_16x16x32_bf16((a),(b),(c),0,0,0)

// =====================================================================
// CONTENT UNIT (R11 structure): 4 independent waves per block, one
// (b,l,m) tile per wave, private 8 KB LDS slice, no hardware barriers.
// Next-phase A-fragment loads hoisted before each fence.
// cu in FRAGMENT ORDER: element (t, d=kk*32+gg*8+j) at ushort offset
// tile*4096 + kk*512 + gg*128 + t*8 + j.
// NEW (R14): FIRST=0 residual is reconstructed from the xb registers
// via cross-lane __shfl (no global re-read of cu: -75.5 MB fetch).
//   lane (t,g), m0 needs d=(m0>>1)*32+gg'*8+(g&1)*4+r, gg'=(m0&1)*2+(g>>1)
//   -> source lane t+16*gg', words of xb[m0>>1]: (g&1)? (z,w):(x,y).
// LDS overlay per tile:
//   0..2048 : HLDS -> AWLDS(0-1024) -> CQLO -> ACLDS(0-1024)
//   2048..4096 : QLDS -> CQHI -> CCHLDS
//   4096..8192 : HT [64][32] (zero-padded cols 16..31)
// Epilogue stages rounded bf16 outputs into 0..8192 for the fused T-mean.
// =====================================================================
template<int FIRST>
__global__ __launch_bounds__(256)
void content_kernel(const void* cusrc_, ushort_t* cudst, float* __restrict__ cm,
                    const float* __restrict__ fm_src, const float* __restrict__ fsg,
                    const float* __restrict__ fsh, const float* __restrict__ dccb,
                    const float* __restrict__ cbq, const float* __restrict__ uccb,
                    const ushort_t* __restrict__ dccf, const ushort_t* __restrict__ cwqf,
                    const ushort_t* __restrict__ uccf, const ushort_t* __restrict__ kcf,
                    const ushort_t* __restrict__ fwhtf)
{
  __shared__ __align__(16) char sm_all[4][8192];
  const int wid = threadIdx.x >> 6;
  const int lane = threadIdx.x & 63;
  char* sm = sm_all[wid];
  const int t = lane & 15, g = lane >> 4;
  const int tile = blockIdx.x*4 + wid;
  const int b = tile / (LL*LL);

  { // zero HT pad cols (s=16..31)
    f4v z = {0.f,0.f,0.f,0.f};
    *(f4v*)(sm + 4096 + ADR32(lane, 32)) = z;
    *(f4v*)(sm + 4096 + ADR32(lane, 48)) = z;
  }

  // ---- X B-fragments: X[t][k], k = kk*32+g*8+j ----
  s8v xb[8];
  if (FIRST){
    const float* xp = (const float*)cusrc_ + (size_t)tile*4096 + t*DD + g*8;
    #pragma unroll
    for (int kk=0;kk<8;kk++){
      f4v lo = *(const f4v*)(xp + kk*32);
      f4v hi = *(const f4v*)(xp + kk*32 + 4);
      s8v v;
      v[0]=(short)f2bf(lo[0]); v[1]=(short)f2bf(lo[1]);
      v[2]=(short)f2bf(lo[2]); v[3]=(short)f2bf(lo[3]);
      v[4]=(short)f2bf(hi[0]); v[5]=(short)f2bf(hi[1]);
      v[6]=(short)f2bf(hi[2]); v[7]=(short)f2bf(hi[3]);
      xb[kk]=v;
    }
  } else {
    // fragment-order cu: fully coalesced (lane*16B within each kk-chunk)
    const ushort_t* xp = (const ushort_t*)cusrc_ + (size_t)tile*4096 + lane*8;
    #pragma unroll
    for (int kk=0;kk<8;kk++) xb[kk] = *(const s8v*)(xp + kk*512);
  }

  // ---- H^T = dcc_w @ X^T + dcc_b ----
  f4v accH[4];
  {
    f4v z = {0.f,0.f,0.f,0.f};
    accH[0]=z; accH[1]=z; accH[2]=z; accH[3]=z;
  }
  #pragma unroll
  for (int kk=0;kk<8;kk++){
    #pragma unroll
    for (int m0=0;m0<4;m0++){
      s8v a = *(const s8v*)(dccf + (((m0<<3)+kk)<<9) + (lane<<3));
      accH[m0] = MFMA(a, xb[kk], accH[m0]);
    }
  }
  // hoisted A-fragments for the Q phase
  s8v cwa[8];
  #pragma unroll
  for (int i=0;i<8;i++) cwa[i] = *(const s8v*)(cwqf + (i<<9) + (lane<<3));
  #pragma unroll
  for (int m0=0;m0<4;m0++){
    f4v acc = accH[m0];
    f4v bi = *(const f4v*)(dccb + m0*16 + g*4);
    acc[0]+=bi[0]; acc[1]+=bi[1]; acc[2]+=bi[2]; acc[3]+=bi[3];
    accH[m0]=acc;
    st64(sm + ADR64(t, m0*32 + g*8), acc[0],acc[1],acc[2],acc[3]);   // HLDS [t][dl]
    #pragma unroll
    for (int r=0;r<4;r++)                                            // HT [dl][t]
      *(ushort_t*)(sm + 4096 + ADR32(m0*16 + g*4 + r, t*2)) = f2bf(acc[r]);
  }
  FENCE();  // A

  // ---- q^T = cWq @ H^T + cbq ----
  s8v hb0 = *(const s8v*)(sm + ADR64(t, g*16));
  s8v hb1 = *(const s8v*)(sm + ADR64(t, 64 + g*16));
  #pragma unroll
  for (int m0=0;m0<4;m0++){
    f4v acc = {0.f,0.f,0.f,0.f};
    acc = MFMA(cwa[m0*2  ], hb0, acc);
    acc = MFMA(cwa[m0*2+1], hb1, acc);
    f4v bi = *(const f4v*)(cbq + m0*16 + g*4);
    st64(sm + 2048 + ADR64(t, m0*32 + g*8),
         acc[0]+bi[0], acc[1]+bi[1], acc[2]+bi[2], acc[3]+bi[3]);    // QLDS
  }
  // hoisted A-fragments for the s phase
  s8v kca[4];
  #pragma unroll
  for (int i=0;i<4;i++) kca[i] = *(const s8v*)(kcf + (b<<11) + (i<<9) + (lane<<3));
  FENCE();  // B

  // ---- s^T = (kc/8) @ q^T ----
  s8v qb0 = *(const s8v*)(sm + 2048 + ADR64(t, g*16));
  s8v qb1 = *(const s8v*)(sm + 2048 + ADR64(t, 64 + g*16));
  f4v sA[2];
  #pragma unroll
  for (int m0=0;m0<2;m0++){
    f4v acc = {0.f,0.f,0.f,0.f};
    acc = MFMA(kca[m0*2  ], qb0, acc);
    acc = MFMA(kca[m0*2+1], qb1, acc);
    sA[m0]=acc;
  }
  // softmax over n
  float mx = -3.0e38f;
  #pragma unroll
  for (int m0=0;m0<2;m0++){
    #pragma unroll
    for (int r=0;r<4;r++){
      int n = m0*16 + g*4 + r;
      if (n < NWW) mx = fmaxf(mx, sA[m0][r]);
    }
  }
  mx = fmaxf(mx, __shfl_xor(mx, 16));
  mx = fmaxf(mx, __shfl_xor(mx, 32));
  float ex[8]; float sum = 0.f;
  #pragma unroll
  for (int m0=0;m0<2;m0++){
    #pragma unroll
    for (int r=0;r<4;r++){
      int n = m0*16 + g*4 + r;
      float e = (n < NWW) ? __expf(sA[m0][r]-mx) : 0.f;
      ex[m0*4+r]=e; sum+=e;
    }
  }
  sum += __shfl_xor(sum,16);
  sum += __shfl_xor(sum,32);
  float inv = 1.f/sum;
  #pragma unroll
  for (int m0=0;m0<2;m0++)
    st64(sm + ADR32(t, m0*32 + g*8),
         ex[m0*4]*inv, ex[m0*4+1]*inv, ex[m0*4+2]*inv, ex[m0*4+3]*inv); // AWLDS @0
  // hoisted A-fragments for the fcaq phase
  s8v fwa[4];
  #pragma unroll
  for (int i=0;i<4;i++) fwa[i] = *(const s8v*)(fwhtf + (b<<11) + (i<<9) + (lane<<3));
  FENCE();  // C

  // ---- f_caq^T = fwh^T @ aw^T ; f_cq (x 8^-0.5, hi/lo split) ----
  s8v awb = *(const s8v*)(sm + ADR32(t, g*16));
  FENCE();  // C2
  #pragma unroll
  for (int m0=0;m0<4;m0++){
    f4v z = {0.f,0.f,0.f,0.f};
    f4v acc = MFMA(fwa[m0], awb, z);
    f4v fv = *(const f4v*)(fsh + b*DLL + m0*16 + g*4);
    float cq0 = accH[m0][0]*(acc[0]+fv[0])*0.35355339059f;
    float cq1 = accH[m0][1]*(acc[1]+fv[1])*0.35355339059f;
    float cq2 = accH[m0][2]*(acc[2]+fv[2])*0.35355339059f;
    float cq3 = accH[m0][3]*(acc[3]+fv[3])*0.35355339059f;
    ushort_t h0=f2bf(cq0),h1=f2bf(cq1),h2=f2bf(cq2),h3=f2bf(cq3);
    uint2 hv; hv.x=(unsigned)h0|((unsigned)h1<<16); hv.y=(unsigned)h2|((unsigned)h3<<16);
    *(uint2*)(sm + 2048 + ADR64(t, m0*32+g*8)) = hv;                 // CQHI @2048
    uint2 lv;
    lv.x = (unsigned)f2bf(cq0-bf2f(h0)) | ((unsigned)f2bf(cq1-bf2f(h1))<<16);
    lv.y = (unsigned)f2bf(cq2-bf2f(h2)) | ((unsigned)f2bf(cq3-bf2f(h3))<<16);
    *(uint2*)(sm + ADR64(t, m0*32+g*8)) = lv;                        // CQLO @0
  }
  FENCE();  // D

  // ---- S2 = f_cq f_cq^T (hh+hl+lh; symmetric) ----
  s8v ch0 = *(const s8v*)(sm + 2048 + ADR64(t, g*16));
  s8v ch1 = *(const s8v*)(sm + 2048 + ADR64(t, 64+g*16));
  s8v cl0 = *(const s8v*)(sm + ADR64(t, g*16));
  s8v cl1 = *(const s8v*)(sm + ADR64(t, 64+g*16));
  f4v s2 = {0.f,0.f,0.f,0.f};
  s2 = MFMA(ch0, ch0, s2); s2 = MFMA(ch1, ch1, s2);
  s2 = MFMA(ch0, cl0, s2); s2 = MFMA(ch1, cl1, s2);
  s2 = MFMA(cl0, ch0, s2); s2 = MFMA(cl1, ch1, s2);
  float mx2 = fmaxf(fmaxf(s2[0],s2[1]), fmaxf(s2[2],s2[3]));
  mx2 = fmaxf(mx2, __shfl_xor(mx2,16));
  mx2 = fmaxf(mx2, __shfl_xor(mx2,32));
  float e0=__expf(s2[0]-mx2), e1=__expf(s2[1]-mx2), e2=__expf(s2[2]-mx2), e3=__expf(s2[3]-mx2);
  float su = e0+e1+e2+e3;
  su += __shfl_xor(su,16);
  su += __shfl_xor(su,32);
  float inv2 = 1.f/su;
  FENCE();  // D2
  st64(sm + ADR32(t, g*8), e0*inv2, e1*inv2, e2*inv2, e3*inv2);      // ACLDS @0
  { uint2 zz; zz.x=0u; zz.y=0u; *(uint2*)(sm + ADR32(t, 32+g*8)) = zz; }
  FENCE();  // E

  // ---- f_cc_hat^T = H^T @ A_c^T  (A from HT, B from ACLDS) ----
  s8v acb = *(const s8v*)(sm + ADR32(t, g*16));
  #pragma unroll
  for (int m0=0;m0<4;m0++){
    s8v a = *(const s8v*)(sm + 4096 + ADR32(m0*16 + t, g*16));
    f4v z = {0.f,0.f,0.f,0.f};
    f4v acc = MFMA(a, acb, z);
    st64(sm + 2048 + ADR64(t, m0*32+g*8), acc[0],acc[1],acc[2],acc[3]); // CCHLDS
  }
  FENCE();  // F

  // ---- f_cc^T = ucc_w @ f_cc_hat^T ; out = f_cc + fc + sigmoid(fm*fs)*fm ----
  s8v cc0 = *(const s8v*)(sm + 2048 + ADR64(t, g*16));
  s8v cc1 = *(const s8v*)(sm + 2048 + ADR64(t, 64+g*16));
  FENCE();  // F2
  const float* fmp = fm_src + (size_t)tile*DD;
  const float* fsp = fsg + b*DD;
  const int frofs = t*8 + (g>>1)*128 + (g&1)*4;
  ushort_t* ofr = cudst + (size_t)tile*4096 + frofs;
  const float* xf = (const float*)cusrc_ + (size_t)tile*4096 + t*DD;  // FIRST=1 path
  #pragma unroll
  for (int m0=0;m0<16;m0++){
    f4v acc = {0.f,0.f,0.f,0.f};
    s8v a0 = *(const s8v*)(uccf + (((m0<<1)  )<<9) + (lane<<3));
    s8v a1 = *(const s8v*)(uccf + (((m0<<1)+1)<<9) + (lane<<3));
    acc = MFMA(a0, cc0, acc);
    acc = MFMA(a1, cc1, acc);
    const int dq = m0*16 + g*4;
    const int fi = (m0>>1)*512 + (m0&1)*256;
    f4v ub  = *(const f4v*)(uccb + dq);
    f4v fmv = *(const f4v*)(fmp + dq);
    f4v fvv = *(const f4v*)(fsp + dq);
    float xr0,xr1,xr2,xr3;
    if (FIRST){
      f4v xv = *(const f4v*)(xf + dq);
      xr0=xv[0]; xr1=xv[1]; xr2=xv[2]; xr3=xv[3];
    } else {
      // residual from xb registers via cross-lane shuffle (no global read)
      uint4 xw = __builtin_bit_cast(uint4, xb[m0>>1]);
      const int srcl = t + (((m0&1)*2 + (g>>1)) << 4);
      unsigned w0 = (unsigned)__shfl((int)xw.x, srcl);
      unsigned w1 = (unsigned)__shfl((int)xw.y, srcl);
      unsigned w2 = (unsigned)__shfl((int)xw.z, srcl);
      unsigned w3 = (unsigned)__shfl((int)xw.w, srcl);
      unsigned rx = (g&1) ? w2 : w0;
      unsigned ry = (g&1) ? w3 : w1;
      xr0=bf2f((ushort_t)(rx&0xffffu)); xr1=bf2f((ushort_t)(rx>>16));
      xr2=bf2f((ushort_t)(ry&0xffffu)); xr3=bf2f((ushort_t)(ry>>16));
    }
    float o0 = acc[0]+ub[0]+xr0 + fmv[0]*__builtin_amdgcn_rcpf(1.f+__expf(-fmv[0]*fvv[0]));
    float o1 = acc[1]+ub[1]+xr1 + fmv[1]*__builtin_amdgcn_rcpf(1.f+__expf(-fmv[1]*fvv[1]));
    float o2 = acc[2]+ub[2]+xr2 + fmv[2]*__builtin_amdgcn_rcpf(1.f+__expf(-fmv[2]*fvv[2]));
    float o3 = acc[3]+ub[3]+xr3 + fmv[3]*__builtin_amdgcn_rcpf(1.f+__expf(-fmv[3]*fvv[3]));
    uint2 ov; ov.x=(unsigned)f2bf(o0)|((unsigned)f2bf(o1)<<16);
    ov.y=(unsigned)f2bf(o2)|((unsigned)f2bf(o3)<<16);
    *(uint2*)(ofr + fi) = ov;                                        // coalesced 8B
    // stage rounded bf16 row into LDS for the fused T-mean
    *(uint2*)(sm + (t<<9) + ((dq*2) ^ ((t&15)<<3))) = ov;
  }
  FENCE();  // G

  // ---- fused meank: cm[tile][d] = mean over t of rounded outputs ----
  {
    const int d0 = lane*4;
    float s0=0.f,s1=0.f,s2=0.f,s3=0.f;
    #pragma unroll
    for (int tt=0;tt<TT;tt++){
      uint2 v = *(const uint2*)(sm + (tt<<9) + ((d0*2) ^ ((tt&15)<<3)));
      s0 += bf2f((ushort_t)(v.x&0xffffu)); s1 += bf2f((ushort_t)(v.x>>16));
      s2 += bf2f((ushort_t)(v.y&0xffffu)); s3 += bf2f((ushort_t)(v.y>>16));
    }
    f4v o = {s0*0.0625f, s1*0.0625f, s2*0.0625f, s3*0.0625f};
    *(f4v*)(cm + (size_t)tile*DD + d0) = o;
  }
}

// =====================================================================
// BOUNDARY UNIT (fp32 VALU; tiny)
// =====================================================================
__global__ __launch_bounds__(256)
void bnd1_kernel(const float* __restrict__ fb, const float* __restrict__ f_w,
                 const float* __restrict__ f_s, const float* __restrict__ kb,
                 const float* __restrict__ bWqT, const float* __restrict__ bbq,
                 float* __restrict__ fbq)
{
  int blk = blockIdx.x; int b = blk / LL, l = blk % LL;
  int d = threadIdx.x;
  __shared__ float fbrow[DD];
  __shared__ float qrow[DD];
  __shared__ float smx[32];
  fbrow[d] = fb[(size_t)(b*LL+l)*DD + d];
  __syncthreads();
  float q = bbq[d];
  for (int e=0;e<DD;e++) q += fbrow[e]*bWqT[(size_t)e*DD+d];
  qrow[d]=q;
  __syncthreads();
  if (d < NWW){
    float s=0.f; const float* kr = kb + (size_t)(b*NWW+d)*DD;
    for (int e=0;e<DD;e++) s += qrow[e]*kr[e];
    smx[d] = s*(1.0f/16.0f);
  }
  __syncthreads();
  if (d==0){
    float m2=-3.0e38f;
    for(int n=0;n<NWW;n++) m2=fmaxf(m2,smx[n]);
    float su=0.f;
    for(int n=0;n<NWW;n++){ float e=__expf(smx[n]-m2); smx[n]=e; su+=e; }
    float iv=1.f/su;
    for(int n=0;n<NWW;n++) smx[n]*=iv;
  }
  __syncthreads();
  float acc=0.f;
  for (int n=0;n<NWW;n++) acc += smx[n]*f_w[(size_t)(b*NWW+n)*DD+d];
  fbq[(size_t)(b*LL+l)*DD+d] = fbrow[d]*(acc + f_s[b*DD+d]);
}

__global__ __launch_bounds__(256)
void bnd2_kernel(const float* __restrict__ fbq, const float* __restrict__ fb,
                 const float* __restrict__ fm, const float* __restrict__ f_s,
                 float* __restrict__ bu_out)
{
  int blk = blockIdx.x; int b = blk/LL, l = blk%LL;
  int d = threadIdx.x;
  __shared__ float Sl[DD];
  __shared__ float aw[LL];
  Sl[d] = fbq[(size_t)(b*LL+l)*DD + d];
  __syncthreads();
  if (d < LL){
    float s=0.f; const float* fr = fbq + (size_t)(b*LL+d)*DD;
    const f4v* s4 = (const f4v*)Sl; const f4v* f4p = (const f4v*)fr;
    for (int e=0;e<DD/4;e++){
      f4v a=s4[e], c=f4p[e];
      s += a[0]*c[0]+a[1]*c[1]+a[2]*c[2]+a[3]*c[3];
    }
    aw[d] = s*(1.0f/16.0f);
  }
  __syncthreads();
  if (d==0){
    float m2=-3.0e38f;
    for(int n=0;n<LL;n++) m2=fmaxf(m2,aw[n]);
    float su=0.f;
    for(int n=0;n<LL;n++){ float e=__expf(aw[n]-m2); aw[n]=e; su+=e; }
    float iv=1.f/su;
    for(int n=0;n<LL;n++) aw[n]*=iv;
  }
  __syncthreads();
  float fsd = f_s[b*DD+d];
  const float* fmrow = fm + ((size_t)(b*LL+l)*LL)*DD + d;
  float acc=0.f;
  for (int m=0;m<LL;m++){
    float a  = aw[m];
    float fbv= fb[(size_t)(b*LL+m)*DD+d];
    float fmv= fmrow[(size_t)m*DD];
    float gm = 1.f/(1.f+__expf(-fmv*fsd));
    acc += a*(fbv + gm*fmv);
  }
  bu_out[(size_t)(b*LL+l)*DD+d] = acc + fb[(size_t)(b*LL+l)*DD+d];
}

// =====================================================================
// MOMENT UNIT — writes mu directly into d_out (fp32)
// =====================================================================
__global__ __launch_bounds__(256)
void moment_kernel(const float* __restrict__ cm, const float* __restrict__ bu,
                   const float* __restrict__ mu_in, float* __restrict__ mu_out,
                   const float* __restrict__ wbT, const float* __restrict__ wcT,
                   const float* __restrict__ mfbb, const float* __restrict__ mfcb)
{
  int blk = blockIdx.x;
  int oh = blk & 1; int bm = blk>>1; int b = bm/LL, m = bm%LL;
  int d = threadIdx.x;
  const int ob = oh*24;
  float accB[24], accC[24];
  #pragma unroll
  for (int o=0;o<24;o++){accB[o]=0.f;accC[o]=0.f;}
  for (int i=0;i<LL;i++){
    float bv = bu[(size_t)(b*LL+i)*DD+d];
    float cv = cm[((size_t)(b*LL+i)*LL+m)*DD+d];
    const float* wb = wbT + i*LL + ob;
    const float* wc = wcT + i*LL + ob;
    #pragma unroll
    for (int o=0;o<24;o+=4){
      f4v w1 = *(const f4v*)(wb+o);
      f4v w2 = *(const f4v*)(wc+o);
      accB[o  ]+=w1[0]*bv; accB[o+1]+=w1[1]*bv; accB[o+2]+=w1[2]*bv; accB[o+3]+=w1[3]*bv;
      accC[o  ]+=w2[0]*cv; accC[o+1]+=w2[1]*cv; accC[o+2]+=w2[2]*cv; accC[o+3]+=w2[3]*cv;
    }
  }
  float bum = bu[(size_t)(b*LL+m)*DD+d];
  #pragma unroll
  for (int o=0;o<24;o++){
    int oo = ob+o;
    size_t oi = ((size_t)(b*LL+oo)*LL+m)*DD + d;
    mu_out[oi] = accB[o]*bum + mfbb[oo] + accC[o] + mfcb[oo] + mu_in[oi];
  }
}

// =====================================================================
// PREP1
// =====================================================================
__global__ __launch_bounds__(256)
void prep1_kernel(const float* __restrict__ f_w, const float* __restrict__ f_s,
                  const float* __restrict__ bWq, const float* __restrict__ bWk,
                  const float* __restrict__ bbk,
                  const float* __restrict__ dcw_w, const float* __restrict__ dcw_b,
                  const float* __restrict__ dcs_w, const float* __restrict__ dcs_b,
                  const float* __restrict__ dcc_w, const float* __restrict__ cWq,
                  const float* __restrict__ ucc_w,
                  const float* __restrict__ mfb_w, const float* __restrict__ mfc_w,
                  float* __restrict__ kb, float* __restrict__ fwh,
                  float* __restrict__ fsh, float* __restrict__ bWqT,
                  ushort_t* __restrict__ dccf, ushort_t* __restrict__ cwqf,
                  ushort_t* __restrict__ uccf,
                  float* __restrict__ wbT, float* __restrict__ wcT)
{
  const int S0=20480, S1=5120, S2=256, S3=65536, S4=16384, S5=4096, S6=16384, S7=2304;
  const int TOT = S0+S1+S2+S3+S4+S5+S6+S7;
  int id = blockIdx.x*256 + threadIdx.x;
  int nth = gridDim.x*256;
  for (int x=id; x<TOT; x+=nth){
    int y=x;
    if (y < S0){
      int b=y/(NWW*DD); int r=y%(NWW*DD); int n=r/DD, dd2=r%DD;
      float s=bbk[dd2];
      const float* fr=f_w+(size_t)(b*NWW+n)*DD; const float* wr=bWk+(size_t)dd2*DD;
      for(int e=0;e<DD;e++) s+=fr[e]*wr[e];
      kb[y]=s; continue; }
    y-=S0;
    if (y < S1){
      int b=y/(NWW*DLL); int r=y%(NWW*DLL); int n=r/DLL, dl=r%DLL;
      float s=dcw_b[dl];
      const float* fr=f_w+(size_t)(b*NWW+n)*DD; const float* wr=dcw_w+(size_t)dl*DD;
      for(int e=0;e<DD;e++) s+=fr[e]*wr[e];
      fwh[y]=s; continue; }
    y-=S1;
    if (y < S2){
      int b=y/DLL, dl=y%DLL;
      float s=dcs_b[dl];
      const float* fr=f_s+(size_t)b*DD; const float* wr=dcs_w+(size_t)dl*DD;
      for(int e=0;e<DD;e++) s+=fr[e]*wr[e];
      fsh[y]=s; continue; }
    y-=S2;
    if (y < S3){ int e=y/DD, dd2=y%DD; bWqT[y] = bWq[(size_t)dd2*DD+e]; continue; }
    y-=S3;
    if (y < S4){
      int j=y&7, ln=(y>>3)&63, kk=(y>>9)&7, m0=y>>12;
      int mm=m0*16+(ln&15), k=kk*32+((ln>>4)<<3)+j;
      dccf[y]=f2bf(dcc_w[(size_t)mm*DD+k]); continue; }
    y-=S4;
    if (y < S5){
      int j=y&7, ln=(y>>3)&63, kk=(y>>9)&1, m0=y>>10;
      int mm=m0*16+(ln&15), k=kk*32+((ln>>4)<<3)+j;
      cwqf[y]=f2bf(cWq[(size_t)mm*DLL+k]); continue; }
    y-=S5;
    if (y < S6){
      int j=y&7, ln=(y>>3)&63, kk=(y>>9)&1, m0=y>>10;
      int mm=m0*16+(ln&15), k=kk*32+((ln>>4)<<3)+j;
      uccf[y]=f2bf(ucc_w[(size_t)mm*DLL+k]); continue; }
    y-=S6;
    { int i=y/LL, o=y%LL; wbT[y]=mfb_w[(size_t)o*LL+i]; wcT[y]=mfc_w[(size_t)o*LL+i]; }
  }
}

// =====================================================================
// PREP2
// =====================================================================
__global__ __launch_bounds__(256)
void prep2_kernel(const float* __restrict__ fwh, const float* __restrict__ cWk,
                  const float* __restrict__ cbk,
                  ushort_t* __restrict__ kcf, ushort_t* __restrict__ fwhtf)
{
  const int S0 = BB*2048, S1 = BB*2048;
  int id = blockIdx.x*256+threadIdx.x; int nth=gridDim.x*256;
  for (int x=id; x<S0+S1; x+=nth){
    int y=x;
    if (y < S0){
      int b=y>>11; int z=y&2047;
      int j=z&7, ln=(z>>3)&63, kk=(z>>9)&1, m0=z>>10;
      int n=m0*16+(ln&15), k=kk*32+((ln>>4)<<3)+j;
      float v=0.f;
      if (n<NWW){
        float s=cbk[k];
        const float* fr=fwh+(size_t)(b*NWW+n)*DLL; const float* wr=cWk+(size_t)k*DLL;
        for(int e=0;e<DLL;e++) s+=fr[e]*wr[e];
        v=s*0.125f;
      }
      kcf[y]=f2bf(v); continue; }
    y-=S0;
    {
      int b=y>>11; int z=y&2047;
      int j=z&7, ln=(z>>3)&63, m0=z>>9;
      int dl=m0*16+(ln&15), n=((ln>>4)<<3)+j;
      float v = (n<NWW)? fwh[(size_t)(b*NWW+n)*DLL+dl] : 0.f;
      fwhtf[y]=f2bf(v);
    }
  }
}

// =====================================================================
extern "C" void kernel_launch(void* const* d_in, const int* in_sizes, int n_in,
                              void* d_out, int out_size, void* d_ws, size_t ws_size,
                              hipStream_t stream)
{
  (void)in_sizes; (void)n_in; (void)out_size; (void)ws_size;
  const float* f_c  = (const float*)d_in[0];
  const float* f_m  = (const float*)d_in[1];
  const float* f_b  = (const float*)d_in[2];
  const float* f_w  = (const float*)d_in[3];
  const float* f_s  = (const float*)d_in[4];
  const float* bWq  = (const float*)d_in[5];
  const float* bbq  = (const float*)d_in[6];
  const float* bWk  = (const float*)d_in[7];
  const float* bbk  = (const float*)d_in[8];
  const float* cWq  = (const float*)d_in[9];
  const float* cbq  = (const float*)d_in[10];
  const float* cWk  = (const float*)d_in[11];
  const float* cbk  = (const float*)d_in[12];
  const float* dcc_w= (const float*)d_in[13];
  const float* dcc_b= (const float*)d_in[14];
  const float* dcw_w= (const float*)d_in[15];
  const float* dcw_b= (const float*)d_in[16];
  const float* dcs_w= (const float*)d_in[17];
  const float* dcs_b= (const float*)d_in[18];
  const float* ucc_w= (const float*)d_in[19];
  const float* ucc_b= (const float*)d_in[20];
  const float* mfb_w= (const float*)d_in[21];
  const float* mfb_b= (const float*)d_in[22];
  const float* mfc_w= (const float*)d_in[23];
  const float* mfc_b= (const float*)d_in[24];

  char* ws = (char*)d_ws;
  ushort_t* cu = (ushort_t*)(ws+OFF_CU);
  float* cmr  = (float*)(ws+OFF_CM);
  float* bu0  = (float*)(ws+OFF_BU0);
  float* bu1  = (float*)(ws+OFF_BU1);
  float* fbq  = (float*)(ws+OFF_FBQ);
  float* fwh  = (float*)(ws+OFF_FWH);
  float* fsh  = (float*)(ws+OFF_FSH);
  float* kb   = (float*)(ws+OFF_KB);
  float* bWqT = (float*)(ws+OFF_BWQT);
  float* wbT  = (float*)(ws+OFF_WBT);
  float* wcT  = (float*)(ws+OFF_WCT);
  ushort_t* dccf = (ushort_t*)(ws+OFF_DCCF);
  ushort_t* cwqf = (ushort_t*)(ws+OFF_CWQF);
  ushort_t* uccf = (ushort_t*)(ws+OFF_UCCF);
  ushort_t* kcf  = (ushort_t*)(ws+OFF_KCF);
  ushort_t* fwhtf= (ushort_t*)(ws+OFF_FWHTF);

  float* mu = (float*)d_out;
  float* out_bu = (float*)d_out + 2359296;

  prep1_kernel<<<128,256,0,stream>>>(f_w,f_s,bWq,bWk,bbk,dcw_w,dcw_b,dcs_w,dcs_b,
                                     dcc_w,cWq,ucc_w,mfb_w,mfc_w,
                                     kb,fwh,fsh,bWqT,dccf,cwqf,uccf,wbT,wcT);
  prep2_kernel<<<32,256,0,stream>>>(fwh,cWk,cbk,kcf,fwhtf);

  float* bu_cur = nullptr;
  for (int it=0; it<3; ++it){
    const float* fmsrc = (it==0)? f_m : mu;
    if (it==0)
      content_kernel<1><<<2304,256,0,stream>>>(f_c, cu, cmr, fmsrc, f_s, fsh, dcc_b, cbq, ucc_b,
                                               dccf,cwqf,uccf,kcf,fwhtf);
    else
      content_kernel<0><<<2304,256,0,stream>>>(cu, cu, cmr, fmsrc, f_s, fsh, dcc_b, cbq, ucc_b,
                                               dccf,cwqf,uccf,kcf,fwhtf);
    const float* fbsrc = (it==0)? f_b : bu_cur;
    float* bunew = (it==2)? out_bu : ((it==0)? bu0 : ((bu_cur==bu0)? bu1 : bu0));
    bnd1_kernel<<<192,256,0,stream>>>(fbsrc, f_w, f_s, kb, bWqT, bbq, fbq);
    bnd2_kernel<<<192,256,0,stream>>>(fbq, fbsrc, fmsrc, f_s, bunew);
    moment_kernel<<<384,256,0,stream>>>(cmr, bunew, fmsrc, mu, wbT, wcT, mfb_b, mfc_b);
    bu_cur = bunew;
  }
}